// Round 2
// baseline (1257.909 us; speedup 1.0000x reference)
//
#include <hip/hip_runtime.h>
#include <math.h>

// Problem constants (match reference)
constexpr int kF    = 32;    // nr_atom_basis
constexpr int kH    = 7;     // heads
constexpr int kC    = 224;   // F*H
constexpr int kRBF  = 50;
constexpr int kCH   = 28;    // edge chunk per node block
constexpr float kCut = 5.0f;
constexpr float kEps = 1e-8f;

__device__ __forceinline__ float silu_f(float a) { return a / (1.f + __expf(-a)); }
__device__ __forceinline__ float tanh_f(float x) {
    x = fminf(fmaxf(x, -15.f), 15.f);
    float e = __expf(2.f * x);
    return (e - 1.f) / (e + 1.f);
}

// ---------------------------------------------------------------------------
// K0: zero histogram + cursors
// ---------------------------------------------------------------------------
__global__ __launch_bounds__(256) void init_kernel(
    int* __restrict__ counts, int* __restrict__ cursor, int N_)
{
    int idx = blockIdx.x * 256 + threadIdx.x;
    if (idx < N_) { counts[idx] = 0; cursor[idx] = 0; }
}

// ---------------------------------------------------------------------------
// K1: per-edge geometry + edge MLP + attention logits; histogram of idx_i
// One thread per edge; weights staged in LDS (broadcast reads).
// ---------------------------------------------------------------------------
__global__ __launch_bounds__(256) void edge_kernel(
    const float* __restrict__ h, const float* __restrict__ x,
    const int* __restrict__ pl, int E_,
    const float* __restrict__ w_in, const float* __restrict__ b_in,
    const float* __restrict__ w_e1, const float* __restrict__ b_e1,
    const float* __restrict__ w_e2, const float* __restrict__ b_e2,
    const float* __restrict__ w_att, const float* __restrict__ b_att,
    float* __restrict__ he_g, float* __restrict__ logit_g,
    float* __restrict__ dir_g, int* __restrict__ counts)
{
    __shared__ float s_win[64 * kRBF];   // (2F, NRBF)
    __shared__ float s_we1[115 * kF];    // (2F+NRBF+1, F)
    __shared__ float s_we2[kF * kF];
    __shared__ float s_watt[kF * kH];
    __shared__ float s_bin[kRBF], s_be1[kF], s_be2[kF], s_batt[kH];

    int t = threadIdx.x;
    for (int idx = t; idx < 64 * kRBF; idx += 256) s_win[idx] = w_in[idx];
    for (int idx = t; idx < 115 * kF; idx += 256) s_we1[idx] = w_e1[idx];
    for (int idx = t; idx < kF * kF; idx += 256) s_we2[idx] = w_e2[idx];
    for (int idx = t; idx < kF * kH; idx += 256) s_watt[idx] = w_att[idx];
    if (t < kRBF) s_bin[t] = b_in[t];
    if (t < kF) { s_be1[t] = b_e1[t]; s_be2[t] = b_e2[t]; }
    if (t < kH) s_batt[t] = b_att[t];
    __syncthreads();

    int e = blockIdx.x * 256 + t;
    if (e >= E_) return;
    int i = pl[e], j = pl[E_ + e];

    float xi0 = x[i * 3 + 0], xi1 = x[i * 3 + 1], xi2 = x[i * 3 + 2];
    float r0 = x[j * 3 + 0] - xi0;
    float r1 = x[j * 3 + 1] - xi1;
    float r2 = x[j * 3 + 2] - xi2;
    float d = sqrtf(r0 * r0 + r1 * r1 + r2 * r2);
    float inv = 1.0f / (d + kEps);
    dir_g[(size_t)e * 3 + 0] = r0 * inv;
    dir_g[(size_t)e * 3 + 1] = r1 * inv;
    dir_g[(size_t)e * 3 + 2] = r2 * inv;

    const float* hi = h + (size_t)i * kF;
    const float* hj = h + (size_t)j * kF;

    // filt = rbf * (h_cat @ w_in + b_in)
    float facc[kRBF];
#pragma unroll
    for (int n = 0; n < kRBF; n++) facc[n] = 0.f;
    for (int f = 0; f < kF; f++) {
        float v = hi[f];
#pragma unroll
        for (int n = 0; n < kRBF; n++) facc[n] += v * s_win[f * kRBF + n];
    }
    for (int f = 0; f < kF; f++) {
        float v = hj[f];
#pragma unroll
        for (int n = 0; n < kRBF; n++) facc[n] += v * s_win[(kF + f) * kRBF + n];
    }
    const float invw = 49.0f / kCut;   // 1/width, centers = n*width
    float dw = d * invw;
#pragma unroll
    for (int n = 0; n < kRBF; n++) {
        float a = dw - (float)n;
        facc[n] = __expf(-0.5f * a * a) * (facc[n] + s_bin[n]);
    }

    // t1 = silu(edge_in @ w_e1 + b_e1); edge_in = [h_i, h_j, filt, d]
    float t1[kF];
#pragma unroll
    for (int o = 0; o < kF; o++) t1[o] = s_be1[o];
    for (int f = 0; f < kF; f++) {
        float v = hi[f];
#pragma unroll
        for (int o = 0; o < kF; o++) t1[o] += v * s_we1[f * kF + o];
    }
    for (int f = 0; f < kF; f++) {
        float v = hj[f];
#pragma unroll
        for (int o = 0; o < kF; o++) t1[o] += v * s_we1[(kF + f) * kF + o];
    }
#pragma unroll
    for (int n = 0; n < kRBF; n++) {
        float v = facc[n];
#pragma unroll
        for (int o = 0; o < kF; o++) t1[o] += v * s_we1[(64 + n) * kF + o];
    }
#pragma unroll
    for (int o = 0; o < kF; o++) t1[o] += d * s_we1[114 * kF + o];
#pragma unroll
    for (int o = 0; o < kF; o++) t1[o] = silu_f(t1[o]);

    // h_ij_edge = t1 @ w_e2 + b_e2
    float he[kF];
#pragma unroll
    for (int o = 0; o < kF; o++) he[o] = s_be2[o];
#pragma unroll
    for (int o = 0; o < kF; o++) {
        float v = t1[o];
#pragma unroll
        for (int o2 = 0; o2 < kF; o2++) he[o2] += v * s_we2[o * kF + o2];
    }
    // store h_ij_edge as float4 x8
    float4* hp = (float4*)(he_g + (size_t)e * kF);
#pragma unroll
    for (int q = 0; q < 8; q++) {
        float4 v4;
        v4.x = he[4 * q + 0]; v4.y = he[4 * q + 1];
        v4.z = he[4 * q + 2]; v4.w = he[4 * q + 3];
        hp[q] = v4;
    }

    // att logits: celu(he @ w_att + b_att, alpha=2) * cutoff(d)
    float aw[kH];
#pragma unroll
    for (int hh = 0; hh < kH; hh++) aw[hh] = s_batt[hh];
#pragma unroll
    for (int f = 0; f < kF; f++) {
        float v = he[f];
#pragma unroll
        for (int hh = 0; hh < kH; hh++) aw[hh] += v * s_watt[f * kH + hh];
    }
    float cut = 0.f;
    if (d < kCut) cut = 0.5f * (__cosf(0.62831853071795864f * d) + 1.f);
#pragma unroll
    for (int hh = 0; hh < kH; hh++) {
        float a = aw[hh];
        a = (a >= 0.f) ? a : 2.f * (__expf(0.5f * a) - 1.f);
        logit_g[(size_t)e * kH + hh] = a * cut;
    }
    atomicAdd(&counts[i], 1);
}

// ---------------------------------------------------------------------------
// K2: exclusive scan of counts -> offsets (single block, 1024 threads)
// ---------------------------------------------------------------------------
__global__ __launch_bounds__(1024) void scan_kernel(
    const int* __restrict__ counts, int* __restrict__ offsets, int n)
{
    __shared__ int buf[1024];
    __shared__ int carry;
    int t = threadIdx.x;
    if (t == 0) carry = 0;
    __syncthreads();
    for (int base = 0; base < n; base += 1024) {
        int v = (base + t < n) ? counts[base + t] : 0;
        buf[t] = v;
        __syncthreads();
        for (int off = 1; off < 1024; off <<= 1) {
            int xv = (t >= off) ? buf[t - off] : 0;
            __syncthreads();
            buf[t] += xv;
            __syncthreads();
        }
        int c0 = carry;
        if (base + t < n) offsets[base + t] = c0 + buf[t] - v;
        int tot = buf[1023];
        __syncthreads();
        if (t == 0) carry = c0 + tot;
        __syncthreads();
    }
    if (t == 0) offsets[n] = carry;
}

// ---------------------------------------------------------------------------
// K3: scatter edges into CSR order
// ---------------------------------------------------------------------------
__global__ __launch_bounds__(256) void scatter_kernel(
    const int* __restrict__ pl, const int* __restrict__ offsets,
    int* __restrict__ cursor, int* __restrict__ sorted, int E_)
{
    int e = blockIdx.x * 256 + threadIdx.x;
    if (e < E_) {
        int i = pl[e];
        int p = atomicAdd(&cursor[i], 1);
        sorted[offsets[i] + p] = e;
    }
}

// ---------------------------------------------------------------------------
// K4: one block per node — scatter-softmax, sem, xmix GEMM, all node MLPs
// ---------------------------------------------------------------------------
__global__ __launch_bounds__(256) void node_kernel(
    const float* __restrict__ h, const float* __restrict__ x, const float* __restrict__ v,
    const float* __restrict__ he_g, const float* __restrict__ logit_g,
    const float* __restrict__ dir_g,
    const int* __restrict__ offsets, const int* __restrict__ sorted,
    const float* __restrict__ wx,
    const float* __restrict__ w_n1, const float* __restrict__ b_n1,
    const float* __restrict__ w_n2, const float* __restrict__ b_n2,
    const float* __restrict__ w_pn1, const float* __restrict__ b_pn1,
    const float* __restrict__ w_pn2, const float* __restrict__ b_pn2,
    const float* __restrict__ w_v1, const float* __restrict__ b_v1,
    const float* __restrict__ w_v2, const float* __restrict__ w_vmix,
    float* __restrict__ out_h, float* __restrict__ out_x, float* __restrict__ out_v,
    int N_)
{
    __shared__ float s_semT[kC][kCH + 1];   // odd-padded rows: conflict-free row writes
    __shared__ float s_he[kCH][kF];
    __shared__ float s_att[kCH][kH];
    __shared__ float s_dir[kCH][3];
    __shared__ int   s_ed[kCH];
    __shared__ float s_m[kH], s_sden[kH];
    __shared__ float s_comb[kC][3];
    __shared__ float s_hisem[kC];
    __shared__ float s_cnsq[kC];
    __shared__ float s_hrow[kF], s_sp1[kF], s_spat[kF], s_n1[kF], s_g1[kF];
    __shared__ float s_gate, s_dv[3];

    int node = blockIdx.x;
    int t = threadIdx.x;
    int base = offsets[node];
    int deg  = offsets[node + 1] - base;

    for (int idx = t; idx < kC; idx += 256) {
        s_hisem[idx] = 0.f;
        s_comb[idx][0] = 0.f; s_comb[idx][1] = 0.f; s_comb[idx][2] = 0.f;
    }
    if (t < kF) s_hrow[t] = h[(size_t)node * kF + t];
    __syncthreads();

    if (deg > 0) {
        // Phase A: per-head segment max + sum(exp)  (7 threads, serial over deg)
        if (t < kH) {
            float m = -1e30f;
            for (int e = 0; e < deg; e++) {
                int ed = sorted[base + e];
                m = fmaxf(m, logit_g[(size_t)ed * kH + t]);
            }
            float s = 0.f;
            for (int e = 0; e < deg; e++) {
                int ed = sorted[base + e];
                s += __expf(logit_g[(size_t)ed * kH + t] - m);
            }
            s_m[t] = m;
            s_sden[t] = 1.0f / s;
        }
        __syncthreads();

        int g = t >> 5, cl = t & 31;
        float cacc[7][3];
#pragma unroll
        for (int m = 0; m < 7; m++) { cacc[m][0] = 0.f; cacc[m][1] = 0.f; cacc[m][2] = 0.f; }

        for (int e0 = 0; e0 < deg; e0 += kCH) {
            int ce = min(kCH, deg - e0);
            if (t < kCH) s_ed[t] = (t < ce) ? sorted[base + e0 + t] : 0;
            __syncthreads();
            // B1: stage per-edge data (zero-padded past ce)
            for (int idx = t; idx < kCH * kF; idx += 256) {
                int el = idx >> 5, f = idx & 31;
                s_he[el][f] = (el < ce) ? he_g[(size_t)s_ed[el] * kF + f] : 0.f;
            }
            for (int idx = t; idx < kCH * kH; idx += 256) {
                int el = idx / kH, hh = idx - el * kH;
                s_att[el][hh] = (el < ce)
                    ? __expf(logit_g[(size_t)s_ed[el] * kH + hh] - s_m[hh]) * s_sden[hh]
                    : 0.f;
            }
            for (int idx = t; idx < kCH * 3; idx += 256) {
                int el = idx / 3, xx = idx - el * 3;
                s_dir[el][xx] = (el < ce) ? dir_g[(size_t)s_ed[el] * 3 + xx] : 0.f;
            }
            __syncthreads();
            // B2: semT[k][el] = he[el][k/7] * att[el][k%7]; row k owned by thread k
            if (t < kC) {
                int f = t / kH, hh = t - f * kH;
                float hsum = 0.f;
#pragma unroll 4
                for (int el = 0; el < kCH; el++) {
                    float sv = s_he[el][f] * s_att[el][hh];
                    s_semT[t][el] = sv;
                    hsum += sv;
                }
                s_hisem[t] += hsum;   // exclusive owner, cross-chunk accumulate
            }
            __syncthreads();
            // B3: T[e][c] = tanh(sem @ wx); k-outer, 28 accumulators/thread
            if (4 * g < ce) {
                float acc[4][7];
#pragma unroll
                for (int e = 0; e < 4; e++)
#pragma unroll
                    for (int m = 0; m < 7; m++) acc[e][m] = 0.f;
                const float* wr = wx + cl;
                for (int kk = 0; kk < kC; kk++) {
                    float s0 = s_semT[kk][4 * g + 0];
                    float s1 = s_semT[kk][4 * g + 1];
                    float s2 = s_semT[kk][4 * g + 2];
                    float s3 = s_semT[kk][4 * g + 3];
                    const float* wkk = wr + kk * kC;
#pragma unroll
                    for (int m = 0; m < 7; m++) {
                        float wv = wkk[32 * m];
                        acc[0][m] += s0 * wv;
                        acc[1][m] += s1 * wv;
                        acc[2][m] += s2 * wv;
                        acc[3][m] += s3 * wv;
                    }
                }
#pragma unroll
                for (int e = 0; e < 4; e++) {
                    float d0 = s_dir[4 * g + e][0];
                    float d1 = s_dir[4 * g + e][1];
                    float d2 = s_dir[4 * g + e][2];
#pragma unroll
                    for (int m = 0; m < 7; m++) {
                        float T = tanh_f(acc[e][m]);
                        cacc[m][0] += T * d0;
                        cacc[m][1] += T * d1;
                        cacc[m][2] += T * d2;
                    }
                }
            }
            __syncthreads();
        }
        // reduce per-group comb partials into LDS
#pragma unroll
        for (int m = 0; m < 7; m++) {
            atomicAdd(&s_comb[cl + 32 * m][0], cacc[m][0]);
            atomicAdd(&s_comb[cl + 32 * m][1], cacc[m][1]);
            atomicAdd(&s_comb[cl + 32 * m][2], cacc[m][2]);
        }
        __syncthreads();
    }

    // Phase C: comb mean + squared norm
    float invc = 1.0f / fmaxf((float)deg, 1.0f);
    for (int idx = t; idx < kC; idx += 256) {
        float a = s_comb[idx][0] * invc;
        float b = s_comb[idx][1] * invc;
        float c2 = s_comb[idx][2] * invc;
        s_comb[idx][0] = a; s_comb[idx][1] = b; s_comb[idx][2] = c2;
        s_cnsq[idx] = a * a + b * b + c2 * c2;
    }
    __syncthreads();

    // Phase D1 (parallel independent branches)
    if (t < kF) {
        float a = b_pn1[t];
        for (int c = 0; c < kC; c++) a += s_cnsq[c] * w_pn1[c * kF + t];
        s_sp1[t] = silu_f(a);
    } else if (t >= 64 && t < 96) {
        int o = t - 64;
        float a = b_v1[o];
        for (int f = 0; f < kF; f++) a += s_hrow[f] * w_v1[f * kF + o];
        s_g1[o] = silu_f(a);
    } else if (t >= 128 && t < 131) {
        int xx = t - 128;
        float a = 0.f;
        for (int c = 0; c < kC; c++) a += w_vmix[c] * s_comb[c][xx];
        s_dv[xx] = a;
    }
    __syncthreads();
    // D2
    if (t < kF) {
        float a = b_pn2[t];
        for (int o = 0; o < kF; o++) a += s_sp1[o] * w_pn2[o * kF + t];
        s_spat[t] = silu_f(a);
    } else if (t == 64) {
        float a = 0.f;
        for (int o = 0; o < kF; o++) a += s_g1[o] * w_v2[o];
        s_gate = 2.f / (1.f + __expf(-a));
    }
    __syncthreads();
    // D3: node_in = [h, h_i_sem, h_i_spatial] @ w_n1
    if (t < kF) {
        float a = b_n1[t];
        for (int f = 0; f < kF; f++) a += s_hrow[f] * w_n1[f * kF + t];
        for (int c = 0; c < kC; c++) a += s_hisem[c] * w_n1[(kF + c) * kF + t];
        for (int f = 0; f < kF; f++) a += s_spat[f] * w_n1[(kF + kC + f) * kF + t];
        s_n1[t] = silu_f(a);
    }
    __syncthreads();
    // D4: outputs
    if (t < kF) {
        float a = b_n2[t];
        for (int o = 0; o < kF; o++) a += s_n1[o] * w_n2[o * kF + t];
        float hu = s_hrow[t] + silu_f(a);
        out_h[(size_t)node * kF + t] = hu;
    } else if (t >= 64 && t < 67) {
        int xx = t - 64;
        float vv = v[(size_t)node * 3 + xx];
        float vu = s_gate * vv + s_dv[xx];
        float xu = x[(size_t)node * 3 + xx] + vu;
        out_v[(size_t)node * 3 + xx] = vu;
        out_x[(size_t)node * 3 + xx] = xu;
    }
}

// ---------------------------------------------------------------------------
extern "C" void kernel_launch(void* const* d_in, const int* in_sizes, int n_in,
                              void* d_out, int out_size, void* d_ws, size_t ws_size,
                              hipStream_t stream)
{
    const float* h      = (const float*)d_in[0];
    const float* x      = (const float*)d_in[1];
    const float* v      = (const float*)d_in[2];
    const int*   pl     = (const int*)d_in[3];
    const float* w_in   = (const float*)d_in[4];
    const float* b_in   = (const float*)d_in[5];
    const float* w_e1   = (const float*)d_in[6];
    const float* b_e1   = (const float*)d_in[7];
    const float* w_e2   = (const float*)d_in[8];
    const float* b_e2   = (const float*)d_in[9];
    const float* w_att  = (const float*)d_in[10];
    const float* b_att  = (const float*)d_in[11];
    const float* w_n1   = (const float*)d_in[12];
    const float* b_n1   = (const float*)d_in[13];
    const float* w_n2   = (const float*)d_in[14];
    const float* b_n2   = (const float*)d_in[15];
    const float* w_pn1  = (const float*)d_in[16];
    const float* b_pn1  = (const float*)d_in[17];
    const float* w_pn2  = (const float*)d_in[18];
    const float* b_pn2  = (const float*)d_in[19];
    const float* w_v1   = (const float*)d_in[20];
    const float* b_v1   = (const float*)d_in[21];
    const float* w_v2   = (const float*)d_in[22];
    const float* w_xmix = (const float*)d_in[23];
    const float* w_vmix = (const float*)d_in[24];

    const int E_ = in_sizes[3] / 2;
    const int N_ = in_sizes[0] / kF;

    // Workspace carve-up (~34.5 MB total)
    char* w = (char*)d_ws;
    float* he_g    = (float*)w; w += (size_t)E_ * kF * 4;
    float* logit_g = (float*)w; w += (size_t)E_ * kH * 4;
    float* dir_g   = (float*)w; w += (size_t)E_ * 3 * 4;
    int* counts    = (int*)w;   w += (size_t)N_ * 4;
    int* offs      = (int*)w;   w += (size_t)(N_ + 1) * 4;
    int* cursor    = (int*)w;   w += (size_t)N_ * 4;
    int* sorted    = (int*)w;   w += (size_t)E_ * 4;

    float* out_h = (float*)d_out;
    float* out_x = out_h + (size_t)N_ * kF;
    float* out_v = out_x + (size_t)N_ * 3;

    init_kernel<<<dim3((N_ + 255) / 256), dim3(256), 0, stream>>>(counts, cursor, N_);

    edge_kernel<<<dim3((E_ + 255) / 256), dim3(256), 0, stream>>>(
        h, x, pl, E_, w_in, b_in, w_e1, b_e1, w_e2, b_e2, w_att, b_att,
        he_g, logit_g, dir_g, counts);

    scan_kernel<<<dim3(1), dim3(1024), 0, stream>>>(counts, offs, N_);

    scatter_kernel<<<dim3((E_ + 255) / 256), dim3(256), 0, stream>>>(
        pl, offs, cursor, sorted, E_);

    node_kernel<<<dim3(N_), dim3(256), 0, stream>>>(
        h, x, v, he_g, logit_g, dir_g, offs, sorted, w_xmix,
        w_n1, b_n1, w_n2, b_n2, w_pn1, b_pn1, w_pn2, b_pn2,
        w_v1, b_v1, w_v2, w_vmix, out_h, out_x, out_v, N_);
}

// Round 3
// 784.442 us; speedup vs baseline: 1.6036x; 1.6036x over previous
//
#include <hip/hip_runtime.h>
#include <math.h>

// Problem constants (match reference)
constexpr int kF    = 32;    // nr_atom_basis
constexpr int kH    = 7;     // heads
constexpr int kC    = 224;   // F*H
constexpr int kRBF  = 50;
constexpr int kTile = 64;    // edges per GEMM tile
constexpr int kPad  = 68;    // semT row stride (16B-aligned, conflict-tolerable)
constexpr float kCut = 5.0f;
constexpr float kEps = 1e-8f;

__device__ __forceinline__ float silu_f(float a) { return a / (1.f + __expf(-a)); }
__device__ __forceinline__ float tanh_f(float x) {
    x = fminf(fmaxf(x, -15.f), 15.f);
    float e = __expf(2.f * x);
    return (e - 1.f) / (e + 1.f);
}

// ---------------------------------------------------------------------------
// K0: zero histogram + cursors
// ---------------------------------------------------------------------------
__global__ __launch_bounds__(256) void init_kernel(
    int* __restrict__ counts, int* __restrict__ cursor, int N_)
{
    int idx = blockIdx.x * 256 + threadIdx.x;
    if (idx < N_) { counts[idx] = 0; cursor[idx] = 0; }
}

// ---------------------------------------------------------------------------
// K1: per-edge geometry + edge MLP + attention logits; histogram of idx_i
// ---------------------------------------------------------------------------
__global__ __launch_bounds__(256) void edge_kernel(
    const float* __restrict__ h, const float* __restrict__ x,
    const int* __restrict__ pl, int E_,
    const float* __restrict__ w_in, const float* __restrict__ b_in,
    const float* __restrict__ w_e1, const float* __restrict__ b_e1,
    const float* __restrict__ w_e2, const float* __restrict__ b_e2,
    const float* __restrict__ w_att, const float* __restrict__ b_att,
    float* __restrict__ he_g, float* __restrict__ logit_g,
    float* __restrict__ dir_g, int* __restrict__ counts)
{
    __shared__ float s_win[64 * kRBF];   // (2F, NRBF)
    __shared__ float s_we1[115 * kF];    // (2F+NRBF+1, F)
    __shared__ float s_we2[kF * kF];
    __shared__ float s_watt[kF * kH];
    __shared__ float s_bin[kRBF], s_be1[kF], s_be2[kF], s_batt[kH];

    int t = threadIdx.x;
    for (int idx = t; idx < 64 * kRBF; idx += 256) s_win[idx] = w_in[idx];
    for (int idx = t; idx < 115 * kF; idx += 256) s_we1[idx] = w_e1[idx];
    for (int idx = t; idx < kF * kF; idx += 256) s_we2[idx] = w_e2[idx];
    for (int idx = t; idx < kF * kH; idx += 256) s_watt[idx] = w_att[idx];
    if (t < kRBF) s_bin[t] = b_in[t];
    if (t < kF) { s_be1[t] = b_e1[t]; s_be2[t] = b_e2[t]; }
    if (t < kH) s_batt[t] = b_att[t];
    __syncthreads();

    int e = blockIdx.x * 256 + t;
    if (e >= E_) return;
    int i = pl[e], j = pl[E_ + e];

    float xi0 = x[i * 3 + 0], xi1 = x[i * 3 + 1], xi2 = x[i * 3 + 2];
    float r0 = x[j * 3 + 0] - xi0;
    float r1 = x[j * 3 + 1] - xi1;
    float r2 = x[j * 3 + 2] - xi2;
    float d = sqrtf(r0 * r0 + r1 * r1 + r2 * r2);
    float inv = 1.0f / (d + kEps);
    dir_g[(size_t)e * 3 + 0] = r0 * inv;
    dir_g[(size_t)e * 3 + 1] = r1 * inv;
    dir_g[(size_t)e * 3 + 2] = r2 * inv;

    const float* hi = h + (size_t)i * kF;
    const float* hj = h + (size_t)j * kF;

    // filt = rbf * (h_cat @ w_in + b_in)
    float facc[kRBF];
#pragma unroll
    for (int n = 0; n < kRBF; n++) facc[n] = 0.f;
    for (int f = 0; f < kF; f++) {
        float v = hi[f];
#pragma unroll
        for (int n = 0; n < kRBF; n++) facc[n] += v * s_win[f * kRBF + n];
    }
    for (int f = 0; f < kF; f++) {
        float v = hj[f];
#pragma unroll
        for (int n = 0; n < kRBF; n++) facc[n] += v * s_win[(kF + f) * kRBF + n];
    }
    const float invw = 49.0f / kCut;
    float dw = d * invw;
#pragma unroll
    for (int n = 0; n < kRBF; n++) {
        float a = dw - (float)n;
        facc[n] = __expf(-0.5f * a * a) * (facc[n] + s_bin[n]);
    }

    // t1 = silu(edge_in @ w_e1 + b_e1)
    float t1[kF];
#pragma unroll
    for (int o = 0; o < kF; o++) t1[o] = s_be1[o];
    for (int f = 0; f < kF; f++) {
        float v = hi[f];
#pragma unroll
        for (int o = 0; o < kF; o++) t1[o] += v * s_we1[f * kF + o];
    }
    for (int f = 0; f < kF; f++) {
        float v = hj[f];
#pragma unroll
        for (int o = 0; o < kF; o++) t1[o] += v * s_we1[(kF + f) * kF + o];
    }
#pragma unroll
    for (int n = 0; n < kRBF; n++) {
        float v = facc[n];
#pragma unroll
        for (int o = 0; o < kF; o++) t1[o] += v * s_we1[(64 + n) * kF + o];
    }
#pragma unroll
    for (int o = 0; o < kF; o++) t1[o] += d * s_we1[114 * kF + o];
#pragma unroll
    for (int o = 0; o < kF; o++) t1[o] = silu_f(t1[o]);

    // h_ij_edge = t1 @ w_e2 + b_e2
    float he[kF];
#pragma unroll
    for (int o = 0; o < kF; o++) he[o] = s_be2[o];
#pragma unroll
    for (int o = 0; o < kF; o++) {
        float v = t1[o];
#pragma unroll
        for (int o2 = 0; o2 < kF; o2++) he[o2] += v * s_we2[o * kF + o2];
    }
    float4* hp = (float4*)(he_g + (size_t)e * kF);
#pragma unroll
    for (int q = 0; q < 8; q++) {
        float4 v4;
        v4.x = he[4 * q + 0]; v4.y = he[4 * q + 1];
        v4.z = he[4 * q + 2]; v4.w = he[4 * q + 3];
        hp[q] = v4;
    }

    // att logits: celu(he @ w_att + b_att, alpha=2) * cutoff(d)
    float aw[kH];
#pragma unroll
    for (int hh = 0; hh < kH; hh++) aw[hh] = s_batt[hh];
#pragma unroll
    for (int f = 0; f < kF; f++) {
        float v = he[f];
#pragma unroll
        for (int hh = 0; hh < kH; hh++) aw[hh] += v * s_watt[f * kH + hh];
    }
    float cut = 0.f;
    if (d < kCut) cut = 0.5f * (__cosf(0.62831853071795864f * d) + 1.f);
#pragma unroll
    for (int hh = 0; hh < kH; hh++) {
        float a = aw[hh];
        a = (a >= 0.f) ? a : 2.f * (__expf(0.5f * a) - 1.f);
        logit_g[(size_t)e * kH + hh] = a * cut;
    }
    atomicAdd(&counts[i], 1);
}

// ---------------------------------------------------------------------------
// K2: exclusive scan of counts -> offsets (single block, 1024 threads)
// ---------------------------------------------------------------------------
__global__ __launch_bounds__(1024) void scan_kernel(
    const int* __restrict__ counts, int* __restrict__ offsets, int n)
{
    __shared__ int buf[1024];
    __shared__ int carry;
    int t = threadIdx.x;
    if (t == 0) carry = 0;
    __syncthreads();
    for (int base = 0; base < n; base += 1024) {
        int v = (base + t < n) ? counts[base + t] : 0;
        buf[t] = v;
        __syncthreads();
        for (int off = 1; off < 1024; off <<= 1) {
            int xv = (t >= off) ? buf[t - off] : 0;
            __syncthreads();
            buf[t] += xv;
            __syncthreads();
        }
        int c0 = carry;
        if (base + t < n) offsets[base + t] = c0 + buf[t] - v;
        int tot = buf[1023];
        __syncthreads();
        if (t == 0) carry = c0 + tot;
        __syncthreads();
    }
    if (t == 0) offsets[n] = carry;
}

// ---------------------------------------------------------------------------
// K3: scatter edges into CSR order
// ---------------------------------------------------------------------------
__global__ __launch_bounds__(256) void scatter_kernel(
    const int* __restrict__ pl, const int* __restrict__ offsets,
    int* __restrict__ cursor, int* __restrict__ sorted, int E_)
{
    int e = blockIdx.x * 256 + threadIdx.x;
    if (e < E_) {
        int i = pl[e];
        int p = atomicAdd(&cursor[i], 1);
        sorted[offsets[i] + p] = e;
    }
}

// ---------------------------------------------------------------------------
// K4: per-node softmax stats (one 64-lane wave per node, online max/sum)
// ---------------------------------------------------------------------------
__global__ __launch_bounds__(256) void stats_kernel(
    const float* __restrict__ logit_g, const int* __restrict__ offsets,
    const int* __restrict__ sorted,
    float* __restrict__ m_g, float* __restrict__ invs_g, int N_)
{
    int wave = threadIdx.x >> 6;
    int lane = threadIdx.x & 63;
    int node = blockIdx.x * 4 + wave;
    if (node >= N_) return;
    int base = offsets[node];
    int deg  = offsets[node + 1] - base;

    for (int hh = 0; hh < kH; hh++) {
        float m = -1e30f, s = 0.f;
        for (int e = lane; e < deg; e += 64) {
            int ed = sorted[base + e];
            float vv = logit_g[(size_t)ed * kH + hh];
            if (vv > m) { s *= __expf(m - vv); m = vv; }
            s += __expf(vv - m);
        }
#pragma unroll
        for (int off = 32; off >= 1; off >>= 1) {
            float mo = __shfl_xor(m, off);
            float so = __shfl_xor(s, off);
            float mn = fmaxf(m, mo);
            s = s * __expf(m - mn) + so * __expf(mo - mn);
            m = mn;
        }
        if (lane == 0) {
            m_g[(size_t)node * kH + hh] = m;
            invs_g[(size_t)node * kH + hh] = (s > 0.f) ? 1.0f / s : 0.f;
        }
    }
}

// ---------------------------------------------------------------------------
// K5: edge-tile GEMM  T = tanh(sem @ wx), comb/hisem scatter via sorted runs
// 64 sorted edges per block, 256 threads. 56 fp32 accumulators/thread.
// ---------------------------------------------------------------------------
__global__ __launch_bounds__(256) void gemm_kernel(
    const float* __restrict__ he_g, const float* __restrict__ logit_g,
    const float* __restrict__ dir_g,
    const int* __restrict__ pl, const int* __restrict__ sorted,
    const float* __restrict__ m_g, const float* __restrict__ invs_g,
    const float* __restrict__ wx, int E_,
    float* __restrict__ comb_g, float* __restrict__ hisem_g)
{
    __shared__ float s_semT[kC][kPad];        // 59.5 KB (stride 68: 16B aligned)
    __shared__ float s_he[kTile][kF + 1];     // +1 pad: conflict-free column gather
    __shared__ float s_att[kTile][kH];
    __shared__ float s_dir[kTile][3];
    __shared__ int   s_node[kTile];
    __shared__ int   s_ed[kTile];

    int t = threadIdx.x;
    int T0 = blockIdx.x * kTile;

    if (t < kTile) {
        int gi = T0 + t;
        int ed = (gi < E_) ? sorted[gi] : -1;
        s_ed[t] = ed;
        s_node[t] = (ed >= 0) ? pl[ed] : -1;
    }
    __syncthreads();

    for (int idx = t; idx < kTile * 3; idx += 256) {
        int e = idx / 3, d = idx - e * 3;
        int ed = s_ed[e];
        s_dir[e][d] = (ed >= 0) ? dir_g[(size_t)ed * 3 + d] : 0.f;
    }
    for (int idx = t; idx < kTile * kH; idx += 256) {
        int e = idx / kH, hh = idx - e * kH;
        int ed = s_ed[e];
        float a = 0.f;
        if (ed >= 0) {
            int nd = s_node[e];
            a = __expf(logit_g[(size_t)ed * kH + hh] - m_g[(size_t)nd * kH + hh])
                * invs_g[(size_t)nd * kH + hh];
        }
        s_att[e][hh] = a;
    }
    for (int idx = t; idx < kTile * 8; idx += 256) {
        int e = idx >> 3, q = idx & 7;
        int ed = s_ed[e];
        float4 v4 = make_float4(0.f, 0.f, 0.f, 0.f);
        if (ed >= 0) v4 = ((const float4*)(he_g + (size_t)ed * kF))[q];
        s_he[e][4 * q + 0] = v4.x; s_he[e][4 * q + 1] = v4.y;
        s_he[e][4 * q + 2] = v4.z; s_he[e][4 * q + 3] = v4.w;
    }
    __syncthreads();

    // build semT[c][e] = he[e][c/7] * att[e][c%7]
    for (int idx = t; idx < kC * kTile; idx += 256) {
        int e = idx & 63, c = idx >> 6;
        s_semT[c][e] = s_he[e][c / kH] * s_att[e][c % kH];
    }
    __syncthreads();

    // hisem: per-column run-compressed segment sums (threads 0..223)
    if (t < kC) {
        float run = 0.f;
        int rn = s_node[0];
        for (int e = 0; e < kTile; e++) {
            int nd = s_node[e];
            if (nd != rn) {
                if (rn >= 0) atomicAdd(&hisem_g[(size_t)rn * kC + t], run);
                run = 0.f; rn = nd;
            }
            run += s_semT[t][e];
        }
        if (rn >= 0) atomicAdd(&hisem_g[(size_t)rn * kC + t], run);
    }

    // GEMM: group g (8 of 32 lanes) owns edges [8g, 8g+8); lane owns cols cl+32m
    int g  = t >> 5;
    int cl = t & 31;
    float acc[8][7];
#pragma unroll
    for (int j = 0; j < 8; j++)
#pragma unroll
        for (int m = 0; m < 7; m++) acc[j][m] = 0.f;

    const float* wxp = wx + cl;
    for (int kk = 0; kk < kC; kk++) {
        float4 sa = *(const float4*)&s_semT[kk][8 * g];
        float4 sb = *(const float4*)&s_semT[kk][8 * g + 4];
        const float* wrow = wxp + (size_t)kk * kC;
        float wv[7];
#pragma unroll
        for (int m = 0; m < 7; m++) wv[m] = wrow[32 * m];
        float sv[8] = {sa.x, sa.y, sa.z, sa.w, sb.x, sb.y, sb.z, sb.w};
#pragma unroll
        for (int j = 0; j < 8; j++)
#pragma unroll
            for (int m = 0; m < 7; m++) acc[j][m] += sv[j] * wv[m];
    }

    // epilogue: tanh, × dir, run-compressed atomic scatter into comb
    float rc[7][3];
#pragma unroll
    for (int m = 0; m < 7; m++) { rc[m][0] = 0.f; rc[m][1] = 0.f; rc[m][2] = 0.f; }
    int rn = -1;
#pragma unroll
    for (int j = 0; j < 8; j++) {
        int e = 8 * g + j;
        int nd = s_node[e];
        if (nd != rn) {
            if (rn >= 0) {
#pragma unroll
                for (int m = 0; m < 7; m++) {
                    size_t bb = (size_t)rn * (3 * kC) + (size_t)(cl + 32 * m);
                    atomicAdd(&comb_g[bb], rc[m][0]);
                    atomicAdd(&comb_g[bb + kC], rc[m][1]);
                    atomicAdd(&comb_g[bb + 2 * kC], rc[m][2]);
                }
            }
#pragma unroll
            for (int m = 0; m < 7; m++) { rc[m][0] = 0.f; rc[m][1] = 0.f; rc[m][2] = 0.f; }
            rn = nd;
        }
        float d0 = s_dir[e][0], d1 = s_dir[e][1], d2 = s_dir[e][2];
#pragma unroll
        for (int m = 0; m < 7; m++) {
            float T = tanh_f(acc[j][m]);
            rc[m][0] += T * d0; rc[m][1] += T * d1; rc[m][2] += T * d2;
        }
    }
    if (rn >= 0) {
#pragma unroll
        for (int m = 0; m < 7; m++) {
            size_t bb = (size_t)rn * (3 * kC) + (size_t)(cl + 32 * m);
            atomicAdd(&comb_g[bb], rc[m][0]);
            atomicAdd(&comb_g[bb + kC], rc[m][1]);
            atomicAdd(&comb_g[bb + 2 * kC], rc[m][2]);
        }
    }
}

// ---------------------------------------------------------------------------
// K6: per-node epilogue MLPs (32-lane group per node, 8 nodes per block)
// ---------------------------------------------------------------------------
__global__ __launch_bounds__(256) void final_kernel(
    const float* __restrict__ h, const float* __restrict__ x, const float* __restrict__ v,
    const float* __restrict__ comb_g, const float* __restrict__ hisem_g,
    const int* __restrict__ offsets,
    const float* __restrict__ w_n1, const float* __restrict__ b_n1,
    const float* __restrict__ w_n2, const float* __restrict__ b_n2,
    const float* __restrict__ w_pn1, const float* __restrict__ b_pn1,
    const float* __restrict__ w_pn2, const float* __restrict__ b_pn2,
    const float* __restrict__ w_v1, const float* __restrict__ b_v1,
    const float* __restrict__ w_v2, const float* __restrict__ w_vmix,
    float* __restrict__ out_h, float* __restrict__ out_x, float* __restrict__ out_v,
    int N_)
{
    __shared__ float s_cnsq[8][kC];
    __shared__ float s_cm[8][3][kC];
    __shared__ float s_h[8][kF], s_sp1[8][kF], s_spat[8][kF], s_n1[8][kF], s_g1[8][kF];
    __shared__ float s_gate[8], s_dv[8][3];

    int grp = threadIdx.x >> 5, ln = threadIdx.x & 31;
    int node = blockIdx.x * 8 + grp;
    bool valid = node < N_;
    int deg = valid ? (offsets[node + 1] - offsets[node]) : 0;
    float invc = 1.f / fmaxf((float)deg, 1.f);

    if (valid) {
        for (int c = ln; c < kC; c += 32) {
            float a  = comb_g[(size_t)node * (3 * kC) + c] * invc;
            float b  = comb_g[(size_t)node * (3 * kC) + kC + c] * invc;
            float cc = comb_g[(size_t)node * (3 * kC) + 2 * kC + c] * invc;
            s_cm[grp][0][c] = a; s_cm[grp][1][c] = b; s_cm[grp][2][c] = cc;
            s_cnsq[grp][c] = a * a + b * b + cc * cc;
        }
        s_h[grp][ln] = h[(size_t)node * kF + ln];
    }
    __syncthreads();
    if (valid) {
        float a = b_pn1[ln];
        for (int c = 0; c < kC; c++) a += s_cnsq[grp][c] * w_pn1[c * kF + ln];
        s_sp1[grp][ln] = silu_f(a);
        float b = b_v1[ln];
        for (int f = 0; f < kF; f++) b += s_h[grp][f] * w_v1[f * kF + ln];
        s_g1[grp][ln] = silu_f(b);
        if (ln < 3) {
            float s = 0.f;
            for (int c = 0; c < kC; c++) s += w_vmix[c] * s_cm[grp][ln][c];
            s_dv[grp][ln] = s;
        }
    }
    __syncthreads();
    if (valid) {
        float a = b_pn2[ln];
        for (int o = 0; o < kF; o++) a += s_sp1[grp][o] * w_pn2[o * kF + ln];
        s_spat[grp][ln] = silu_f(a);
        if (ln == 0) {
            float s = 0.f;
            for (int o = 0; o < kF; o++) s += s_g1[grp][o] * w_v2[o];
            s_gate[grp] = 2.f / (1.f + __expf(-s));
        }
    }
    __syncthreads();
    if (valid) {
        float a = b_n1[ln];
        for (int f = 0; f < kF; f++) a += s_h[grp][f] * w_n1[f * kF + ln];
        for (int c = 0; c < kC; c++)
            a += hisem_g[(size_t)node * kC + c] * w_n1[(kF + c) * kF + ln];
        for (int f = 0; f < kF; f++) a += s_spat[grp][f] * w_n1[(kF + kC + f) * kF + ln];
        s_n1[grp][ln] = silu_f(a);
    }
    __syncthreads();
    if (valid) {
        float a = b_n2[ln];
        for (int o = 0; o < kF; o++) a += s_n1[grp][o] * w_n2[o * kF + ln];
        out_h[(size_t)node * kF + ln] = s_h[grp][ln] + silu_f(a);
        if (ln < 3) {
            float vv = v[(size_t)node * 3 + ln];
            float vu = s_gate[grp] * vv + s_dv[grp][ln];
            out_v[(size_t)node * 3 + ln] = vu;
            out_x[(size_t)node * 3 + ln] = x[(size_t)node * 3 + ln] + vu;
        }
    }
}

// ---------------------------------------------------------------------------
extern "C" void kernel_launch(void* const* d_in, const int* in_sizes, int n_in,
                              void* d_out, int out_size, void* d_ws, size_t ws_size,
                              hipStream_t stream)
{
    const float* h      = (const float*)d_in[0];
    const float* x      = (const float*)d_in[1];
    const float* v      = (const float*)d_in[2];
    const int*   pl     = (const int*)d_in[3];
    const float* w_in   = (const float*)d_in[4];
    const float* b_in   = (const float*)d_in[5];
    const float* w_e1   = (const float*)d_in[6];
    const float* b_e1   = (const float*)d_in[7];
    const float* w_e2   = (const float*)d_in[8];
    const float* b_e2   = (const float*)d_in[9];
    const float* w_att  = (const float*)d_in[10];
    const float* b_att  = (const float*)d_in[11];
    const float* w_n1   = (const float*)d_in[12];
    const float* b_n1   = (const float*)d_in[13];
    const float* w_n2   = (const float*)d_in[14];
    const float* b_n2   = (const float*)d_in[15];
    const float* w_pn1  = (const float*)d_in[16];
    const float* b_pn1  = (const float*)d_in[17];
    const float* w_pn2  = (const float*)d_in[18];
    const float* b_pn2  = (const float*)d_in[19];
    const float* w_v1   = (const float*)d_in[20];
    const float* b_v1   = (const float*)d_in[21];
    const float* w_v2   = (const float*)d_in[22];
    const float* w_xmix = (const float*)d_in[23];
    const float* w_vmix = (const float*)d_in[24];

    const int E_ = in_sizes[3] / 2;
    const int N_ = in_sizes[0] / kF;

    // Workspace carve-up (~71 MB)
    char* w = (char*)d_ws;
    float* he_g    = (float*)w; w += (size_t)E_ * kF * 4;
    float* logit_g = (float*)w; w += (size_t)E_ * kH * 4;
    float* dir_g   = (float*)w; w += (size_t)E_ * 3 * 4;
    int* counts    = (int*)w;   w += (size_t)N_ * 4;
    int* offs      = (int*)w;   w += (size_t)(N_ + 1) * 4;
    int* cursor    = (int*)w;   w += (size_t)N_ * 4;
    int* sorted    = (int*)w;   w += (size_t)E_ * 4;
    float* m_g     = (float*)w; w += (size_t)N_ * kH * 4;
    float* invs_g  = (float*)w; w += (size_t)N_ * kH * 4;
    float* comb_g  = (float*)w; w += (size_t)N_ * 3 * kC * 4;   // contiguous with hisem
    float* hisem_g = (float*)w; w += (size_t)N_ * kC * 4;

    float* out_h = (float*)d_out;
    float* out_x = out_h + (size_t)N_ * kF;
    float* out_v = out_x + (size_t)N_ * 3;

    init_kernel<<<dim3((N_ + 255) / 256), dim3(256), 0, stream>>>(counts, cursor, N_);

    // zero accumulation buffers (comb + hisem are adjacent: one memset)
    hipMemsetAsync(comb_g, 0, (size_t)N_ * 4 * kC * 4, stream);

    edge_kernel<<<dim3((E_ + 255) / 256), dim3(256), 0, stream>>>(
        h, x, pl, E_, w_in, b_in, w_e1, b_e1, w_e2, b_e2, w_att, b_att,
        he_g, logit_g, dir_g, counts);

    scan_kernel<<<dim3(1), dim3(1024), 0, stream>>>(counts, offs, N_);

    scatter_kernel<<<dim3((E_ + 255) / 256), dim3(256), 0, stream>>>(
        pl, offs, cursor, sorted, E_);

    stats_kernel<<<dim3((N_ + 3) / 4), dim3(256), 0, stream>>>(
        logit_g, offs, sorted, m_g, invs_g, N_);

    gemm_kernel<<<dim3((E_ + kTile - 1) / kTile), dim3(256), 0, stream>>>(
        he_g, logit_g, dir_g, pl, sorted, m_g, invs_g, w_xmix, E_,
        comb_g, hisem_g);

    final_kernel<<<dim3((N_ + 7) / 8), dim3(256), 0, stream>>>(
        h, x, v, comb_g, hisem_g, offs,
        w_n1, b_n1, w_n2, b_n2, w_pn1, b_pn1, w_pn2, b_pn2,
        w_v1, b_v1, w_v2, w_vmix, out_h, out_x, out_v, N_);
}

// Round 4
// 730.713 us; speedup vs baseline: 1.7215x; 1.0735x over previous
//
#include <hip/hip_runtime.h>
#include <math.h>

typedef unsigned short u16;
typedef __attribute__((ext_vector_type(8))) short bf16x8;
typedef __attribute__((ext_vector_type(4))) float f32x4;

// Problem constants (match reference)
constexpr int kF    = 32;    // nr_atom_basis
constexpr int kH    = 7;     // heads
constexpr int kC    = 224;   // F*H
constexpr int kRBF  = 50;
constexpr int kM    = 128;   // edges per xmix block
constexpr int kStr  = 232;   // sem LDS row stride (bf16 elems; 464B, 16B-aligned)
constexpr float kCut = 5.0f;
constexpr float kEps = 1e-8f;

__device__ __forceinline__ float silu_f(float a) { return a / (1.f + __expf(-a)); }
__device__ __forceinline__ float tanh_f(float x) {
    x = fminf(fmaxf(x, -15.f), 15.f);
    float e = __expf(2.f * x);
    return (e - 1.f) / (e + 1.f);
}
__device__ __forceinline__ float bf2f(u16 u) {
    union { unsigned int i; float f; } v; v.i = ((unsigned int)u) << 16; return v.f;
}
__device__ __forceinline__ u16 f2bf(float f) {
    union { float f; unsigned int i; } v; v.f = f;
    unsigned int x = v.i;
    unsigned int round = ((x >> 16) & 1u) + 0x7fffu;
    return (u16)((x + round) >> 16);
}

// ---------------------------------------------------------------------------
// K0: zero histogram + cursors; build wxT (bf16, transposed w_xmix)
// ---------------------------------------------------------------------------
__global__ __launch_bounds__(256) void init_kernel(
    const float* __restrict__ wx, u16* __restrict__ wxT,
    int* __restrict__ counts, int* __restrict__ cursor, int N_)
{
    int idx = blockIdx.x * 256 + threadIdx.x;
    if (idx < kC * kC) {
        int c = idx / kC, k = idx - c * kC;      // wxT[c][k] = wx[k][c]
        wxT[idx] = f2bf(wx[k * kC + c]);
    }
    if (idx < N_) { counts[idx] = 0; cursor[idx] = 0; }
}

// ---------------------------------------------------------------------------
// K1: per-edge geometry + edge MLP + attention logits; histogram of idx_i
// ---------------------------------------------------------------------------
__global__ __launch_bounds__(256) void edge_kernel(
    const float* __restrict__ h, const float* __restrict__ x,
    const int* __restrict__ pl, int E_,
    const float* __restrict__ w_in, const float* __restrict__ b_in,
    const float* __restrict__ w_e1, const float* __restrict__ b_e1,
    const float* __restrict__ w_e2, const float* __restrict__ b_e2,
    const float* __restrict__ w_att, const float* __restrict__ b_att,
    float* __restrict__ he_g, float* __restrict__ logit_g,
    float* __restrict__ dir_g, int* __restrict__ counts)
{
    __shared__ float s_win[64 * kRBF];   // (2F, NRBF)
    __shared__ float s_we1[115 * kF];    // (2F+NRBF+1, F)
    __shared__ float s_we2[kF * kF];
    __shared__ float s_watt[kF * kH];
    __shared__ float s_bin[kRBF], s_be1[kF], s_be2[kF], s_batt[kH];

    int t = threadIdx.x;
    for (int idx = t; idx < 64 * kRBF; idx += 256) s_win[idx] = w_in[idx];
    for (int idx = t; idx < 115 * kF; idx += 256) s_we1[idx] = w_e1[idx];
    for (int idx = t; idx < kF * kF; idx += 256) s_we2[idx] = w_e2[idx];
    for (int idx = t; idx < kF * kH; idx += 256) s_watt[idx] = w_att[idx];
    if (t < kRBF) s_bin[t] = b_in[t];
    if (t < kF) { s_be1[t] = b_e1[t]; s_be2[t] = b_e2[t]; }
    if (t < kH) s_batt[t] = b_att[t];
    __syncthreads();

    int e = blockIdx.x * 256 + t;
    if (e >= E_) return;
    int i = pl[e], j = pl[E_ + e];

    float xi0 = x[i * 3 + 0], xi1 = x[i * 3 + 1], xi2 = x[i * 3 + 2];
    float r0 = x[j * 3 + 0] - xi0;
    float r1 = x[j * 3 + 1] - xi1;
    float r2 = x[j * 3 + 2] - xi2;
    float d = sqrtf(r0 * r0 + r1 * r1 + r2 * r2);
    float inv = 1.0f / (d + kEps);
    dir_g[(size_t)e * 3 + 0] = r0 * inv;
    dir_g[(size_t)e * 3 + 1] = r1 * inv;
    dir_g[(size_t)e * 3 + 2] = r2 * inv;

    const float* hi = h + (size_t)i * kF;
    const float* hj = h + (size_t)j * kF;

    // filt = rbf * (h_cat @ w_in + b_in)
    float facc[kRBF];
#pragma unroll
    for (int n = 0; n < kRBF; n++) facc[n] = 0.f;
    for (int f = 0; f < kF; f++) {
        float v = hi[f];
#pragma unroll
        for (int n = 0; n < kRBF; n++) facc[n] += v * s_win[f * kRBF + n];
    }
    for (int f = 0; f < kF; f++) {
        float v = hj[f];
#pragma unroll
        for (int n = 0; n < kRBF; n++) facc[n] += v * s_win[(kF + f) * kRBF + n];
    }
    const float invw = 49.0f / kCut;
    float dw = d * invw;
#pragma unroll
    for (int n = 0; n < kRBF; n++) {
        float a = dw - (float)n;
        facc[n] = __expf(-0.5f * a * a) * (facc[n] + s_bin[n]);
    }

    // t1 = silu(edge_in @ w_e1 + b_e1)
    float t1[kF];
#pragma unroll
    for (int o = 0; o < kF; o++) t1[o] = s_be1[o];
    for (int f = 0; f < kF; f++) {
        float v = hi[f];
#pragma unroll
        for (int o = 0; o < kF; o++) t1[o] += v * s_we1[f * kF + o];
    }
    for (int f = 0; f < kF; f++) {
        float v = hj[f];
#pragma unroll
        for (int o = 0; o < kF; o++) t1[o] += v * s_we1[(kF + f) * kF + o];
    }
#pragma unroll
    for (int n = 0; n < kRBF; n++) {
        float v = facc[n];
#pragma unroll
        for (int o = 0; o < kF; o++) t1[o] += v * s_we1[(64 + n) * kF + o];
    }
#pragma unroll
    for (int o = 0; o < kF; o++) t1[o] += d * s_we1[114 * kF + o];
#pragma unroll
    for (int o = 0; o < kF; o++) t1[o] = silu_f(t1[o]);

    // h_ij_edge = t1 @ w_e2 + b_e2
    float he[kF];
#pragma unroll
    for (int o = 0; o < kF; o++) he[o] = s_be2[o];
#pragma unroll
    for (int o = 0; o < kF; o++) {
        float v = t1[o];
#pragma unroll
        for (int o2 = 0; o2 < kF; o2++) he[o2] += v * s_we2[o * kF + o2];
    }
    float4* hp = (float4*)(he_g + (size_t)e * kF);
#pragma unroll
    for (int q = 0; q < 8; q++) {
        float4 v4;
        v4.x = he[4 * q + 0]; v4.y = he[4 * q + 1];
        v4.z = he[4 * q + 2]; v4.w = he[4 * q + 3];
        hp[q] = v4;
    }

    // att logits: celu(he @ w_att + b_att, alpha=2) * cutoff(d)
    float aw[kH];
#pragma unroll
    for (int hh = 0; hh < kH; hh++) aw[hh] = s_batt[hh];
#pragma unroll
    for (int f = 0; f < kF; f++) {
        float v = he[f];
#pragma unroll
        for (int hh = 0; hh < kH; hh++) aw[hh] += v * s_watt[f * kH + hh];
    }
    float cut = 0.f;
    if (d < kCut) cut = 0.5f * (__cosf(0.62831853071795864f * d) + 1.f);
#pragma unroll
    for (int hh = 0; hh < kH; hh++) {
        float a = aw[hh];
        a = (a >= 0.f) ? a : 2.f * (__expf(0.5f * a) - 1.f);
        logit_g[(size_t)e * kH + hh] = a * cut;
    }
    atomicAdd(&counts[i], 1);
}

// ---------------------------------------------------------------------------
// K2: exclusive scan of counts -> offsets (single block, 1024 threads)
// ---------------------------------------------------------------------------
__global__ __launch_bounds__(1024) void scan_kernel(
    const int* __restrict__ counts, int* __restrict__ offsets, int n)
{
    __shared__ int buf[1024];
    __shared__ int carry;
    int t = threadIdx.x;
    if (t == 0) carry = 0;
    __syncthreads();
    for (int base = 0; base < n; base += 1024) {
        int v = (base + t < n) ? counts[base + t] : 0;
        buf[t] = v;
        __syncthreads();
        for (int off = 1; off < 1024; off <<= 1) {
            int xv = (t >= off) ? buf[t - off] : 0;
            __syncthreads();
            buf[t] += xv;
            __syncthreads();
        }
        int c0 = carry;
        if (base + t < n) offsets[base + t] = c0 + buf[t] - v;
        int tot = buf[1023];
        __syncthreads();
        if (t == 0) carry = c0 + tot;
        __syncthreads();
    }
    if (t == 0) offsets[n] = carry;
}

// ---------------------------------------------------------------------------
// K3: scatter edges into CSR order
// ---------------------------------------------------------------------------
__global__ __launch_bounds__(256) void scatter_kernel(
    const int* __restrict__ pl, const int* __restrict__ offsets,
    int* __restrict__ cursor, int* __restrict__ sorted, int E_)
{
    int e = blockIdx.x * 256 + threadIdx.x;
    if (e < E_) {
        int i = pl[e];
        int p = atomicAdd(&cursor[i], 1);
        sorted[offsets[i] + p] = e;
    }
}

// ---------------------------------------------------------------------------
// K4: per-node softmax stats (one 64-lane wave per node, online max/sum)
// ---------------------------------------------------------------------------
__global__ __launch_bounds__(256) void stats_kernel(
    const float* __restrict__ logit_g, const int* __restrict__ offsets,
    const int* __restrict__ sorted,
    float* __restrict__ m_g, float* __restrict__ invs_g, int N_)
{
    int wave = threadIdx.x >> 6;
    int lane = threadIdx.x & 63;
    int node = blockIdx.x * 4 + wave;
    if (node >= N_) return;
    int base = offsets[node];
    int deg  = offsets[node + 1] - base;

    for (int hh = 0; hh < kH; hh++) {
        float m = -1e30f, s = 0.f;
        for (int e = lane; e < deg; e += 64) {
            int ed = sorted[base + e];
            float vv = logit_g[(size_t)ed * kH + hh];
            if (vv > m) { s *= __expf(m - vv); m = vv; }
            s += __expf(vv - m);
        }
#pragma unroll
        for (int off = 32; off >= 1; off >>= 1) {
            float mo = __shfl_xor(m, off);
            float so = __shfl_xor(s, off);
            float mn = fmaxf(m, mo);
            s = s * __expf(m - mn) + so * __expf(mo - mn);
            m = mn;
        }
        if (lane == 0) {
            m_g[(size_t)node * kH + hh] = m;
            invs_g[(size_t)node * kH + hh] = (s > 0.f) ? 1.0f / s : 0.f;
        }
    }
}

// ---------------------------------------------------------------------------
// K5: MFMA xmix kernel. 128 sorted edges/block, 256 threads (4 waves).
// sem (bf16) in LDS, wxT (bf16) streamed from global, fp32 MFMA accumulate,
// fused tanh + dir + run-compressed atomic scatter epilogue.
// ---------------------------------------------------------------------------
__global__ __launch_bounds__(256) void xmix_kernel(
    const float* __restrict__ he_g, const float* __restrict__ logit_g,
    const float* __restrict__ dir_g,
    const int* __restrict__ pl, const int* __restrict__ sorted,
    const float* __restrict__ m_g, const float* __restrict__ invs_g,
    const u16* __restrict__ wxT, int E_,
    float* __restrict__ comb_g, float* __restrict__ hisem_g)
{
    __shared__ u16   s_sem[kM][kStr];      // 59392 B
    __shared__ float s_att[kM][kH];        // 3584 B
    __shared__ float s_dir[kM][3];         // 1536 B
    __shared__ int   s_node[kM];           // 512 B
    __shared__ int   s_ed[kM];             // 512 B  (total 65536 B -> 2 blk/CU)

    int t = threadIdx.x;
    int T0 = blockIdx.x * kM;

    if (t < kM) {
        int gi = T0 + t;
        int ed = (gi < E_) ? sorted[gi] : -1;
        s_ed[t] = ed;
        s_node[t] = (ed >= 0) ? pl[ed] : -1;
    }
    __syncthreads();

    // stage dir + att
    for (int idx = t; idx < kM * 3; idx += 256) {
        int e = idx / 3, d = idx - e * 3;
        int ed = s_ed[e];
        s_dir[e][d] = (ed >= 0) ? dir_g[(size_t)ed * 3 + d] : 0.f;
    }
    for (int idx = t; idx < kM * kH; idx += 256) {
        int e = idx / kH, hh = idx - e * kH;
        int ed = s_ed[e];
        float a = 0.f;
        if (ed >= 0) {
            int nd = s_node[e];
            a = __expf(logit_g[(size_t)ed * kH + hh] - m_g[(size_t)nd * kH + hh])
                * invs_g[(size_t)nd * kH + hh];
        }
        s_att[e][hh] = a;
    }
    __syncthreads();

    // build sem[e][c] = he[e][c/7] * att[e][c%7] in bf16; thread owns (e, f)
#pragma unroll
    for (int p = 0; p < kM * kF / 256; p++) {       // 16 iters
        int idx = t + 256 * p;
        int e = idx >> 5, f = idx & 31;
        int ed = s_ed[e];
        float hv = (ed >= 0) ? he_g[(size_t)ed * kF + f] : 0.f;
        u16 sw[7];
#pragma unroll
        for (int hh = 0; hh < kH; hh++) sw[hh] = f2bf(hv * s_att[e][hh]);
        u16* dst = &s_sem[e][f * 7];
        if ((f & 1) == 0) {
            *(unsigned int*)(dst)     = (unsigned int)sw[0] | ((unsigned int)sw[1] << 16);
            *(unsigned int*)(dst + 2) = (unsigned int)sw[2] | ((unsigned int)sw[3] << 16);
            *(unsigned int*)(dst + 4) = (unsigned int)sw[4] | ((unsigned int)sw[5] << 16);
            dst[6] = sw[6];
        } else {
            dst[0] = sw[0];
            *(unsigned int*)(dst + 1) = (unsigned int)sw[1] | ((unsigned int)sw[2] << 16);
            *(unsigned int*)(dst + 3) = (unsigned int)sw[3] | ((unsigned int)sw[4] << 16);
            *(unsigned int*)(dst + 5) = (unsigned int)sw[5] | ((unsigned int)sw[6] << 16);
        }
    }
    __syncthreads();

    // hisem: per-column run-compressed segment sums (threads 0..223)
    if (t < kC) {
        float run = 0.f;
        int rn = s_node[0];
        for (int e = 0; e < kM; e++) {
            int nd = s_node[e];
            if (nd != rn) {
                if (rn >= 0) atomicAdd(&hisem_g[(size_t)rn * kC + t], run);
                run = 0.f; rn = nd;
            }
            run += bf2f(s_sem[e][t]);
        }
        if (rn >= 0) atomicAdd(&hisem_g[(size_t)rn * kC + t], run);
    }

    // MFMA: wave w owns edges [32w, 32w+32) = 2 row-tiles of 16
    int w    = t >> 6;
    int lane = t & 63;
    int quad = lane >> 4;
    int l15  = lane & 15;

    // persistent A-fragments: ds_read_b128, 56 VGPRs
    bf16x8 afr[2][7];
#pragma unroll
    for (int rt = 0; rt < 2; rt++)
#pragma unroll
        for (int kt = 0; kt < 7; kt++)
            afr[rt][kt] = *(const bf16x8*)&s_sem[32 * w + 16 * rt + l15][kt * 32 + quad * 8];

    bf16x8 bA[7], bB[7];
    {
        const u16* bp = wxT + (size_t)l15 * kC + quad * 8;
#pragma unroll
        for (int kt = 0; kt < 7; kt++) bA[kt] = *(const bf16x8*)(bp + kt * 32);
    }

    for (int ct = 0; ct < 14; ct++) {
        bf16x8* cur = (ct & 1) ? bB : bA;
        bf16x8* nxt = (ct & 1) ? bA : bB;
        if (ct < 13) {
            const u16* bp = wxT + (size_t)((ct + 1) * 16 + l15) * kC + quad * 8;
#pragma unroll
            for (int kt = 0; kt < 7; kt++) nxt[kt] = *(const bf16x8*)(bp + kt * 32);
        }
        f32x4 acc0 = {0.f, 0.f, 0.f, 0.f};
        f32x4 acc1 = {0.f, 0.f, 0.f, 0.f};
#pragma unroll
        for (int kt = 0; kt < 7; kt++) {
            acc0 = __builtin_amdgcn_mfma_f32_16x16x32_bf16(afr[0][kt], cur[kt], acc0, 0, 0, 0);
            acc1 = __builtin_amdgcn_mfma_f32_16x16x32_bf16(afr[1][kt], cur[kt], acc1, 0, 0, 0);
        }

        // epilogue: tanh -> * dir -> run-compressed atomics. C/D layout:
        // reg r of accX holds row (32w + 16*X + quad*4 + r), col = ct*16 + l15.
        int colg = ct * 16 + l15;
#pragma unroll
        for (int s = 0; s < 2; s++) {
            f32x4 ac = s ? acc1 : acc0;
            int rbase = 32 * w + 16 * s + quad * 4;
            float r0 = 0.f, r1 = 0.f, r2 = 0.f;
            int rn = -1;
#pragma unroll
            for (int r = 0; r < 4; r++) {
                int e = rbase + r;
                int nd = s_node[e];
                if (nd != rn) {
                    if (rn >= 0) {
                        size_t bb = (size_t)rn * (3 * kC) + colg;
                        atomicAdd(&comb_g[bb], r0);
                        atomicAdd(&comb_g[bb + kC], r1);
                        atomicAdd(&comb_g[bb + 2 * kC], r2);
                    }
                    r0 = r1 = r2 = 0.f; rn = nd;
                }
                float T = tanh_f(ac[r]);
                r0 += T * s_dir[e][0];
                r1 += T * s_dir[e][1];
                r2 += T * s_dir[e][2];
            }
            if (rn >= 0) {
                size_t bb = (size_t)rn * (3 * kC) + colg;
                atomicAdd(&comb_g[bb], r0);
                atomicAdd(&comb_g[bb + kC], r1);
                atomicAdd(&comb_g[bb + 2 * kC], r2);
            }
        }
    }
}

// ---------------------------------------------------------------------------
// K6: per-node epilogue MLPs (32-lane group per node, 8 nodes per block)
// ---------------------------------------------------------------------------
__global__ __launch_bounds__(256) void final_kernel(
    const float* __restrict__ h, const float* __restrict__ x, const float* __restrict__ v,
    const float* __restrict__ comb_g, const float* __restrict__ hisem_g,
    const int* __restrict__ offsets,
    const float* __restrict__ w_n1, const float* __restrict__ b_n1,
    const float* __restrict__ w_n2, const float* __restrict__ b_n2,
    const float* __restrict__ w_pn1, const float* __restrict__ b_pn1,
    const float* __restrict__ w_pn2, const float* __restrict__ b_pn2,
    const float* __restrict__ w_v1, const float* __restrict__ b_v1,
    const float* __restrict__ w_v2, const float* __restrict__ w_vmix,
    float* __restrict__ out_h, float* __restrict__ out_x, float* __restrict__ out_v,
    int N_)
{
    __shared__ float s_cnsq[8][kC];
    __shared__ float s_cm[8][3][kC];
    __shared__ float s_h[8][kF], s_sp1[8][kF], s_spat[8][kF], s_n1[8][kF], s_g1[8][kF];
    __shared__ float s_gate[8], s_dv[8][3];

    int grp = threadIdx.x >> 5, ln = threadIdx.x & 31;
    int node = blockIdx.x * 8 + grp;
    bool valid = node < N_;
    int deg = valid ? (offsets[node + 1] - offsets[node]) : 0;
    float invc = 1.f / fmaxf((float)deg, 1.f);

    if (valid) {
        for (int c = ln; c < kC; c += 32) {
            float a  = comb_g[(size_t)node * (3 * kC) + c] * invc;
            float b  = comb_g[(size_t)node * (3 * kC) + kC + c] * invc;
            float cc = comb_g[(size_t)node * (3 * kC) + 2 * kC + c] * invc;
            s_cm[grp][0][c] = a; s_cm[grp][1][c] = b; s_cm[grp][2][c] = cc;
            s_cnsq[grp][c] = a * a + b * b + cc * cc;
        }
        s_h[grp][ln] = h[(size_t)node * kF + ln];
    }
    __syncthreads();
    if (valid) {
        float a = b_pn1[ln];
        for (int c = 0; c < kC; c++) a += s_cnsq[grp][c] * w_pn1[c * kF + ln];
        s_sp1[grp][ln] = silu_f(a);
        float b = b_v1[ln];
        for (int f = 0; f < kF; f++) b += s_h[grp][f] * w_v1[f * kF + ln];
        s_g1[grp][ln] = silu_f(b);
        if (ln < 3) {
            float s = 0.f;
            for (int c = 0; c < kC; c++) s += w_vmix[c] * s_cm[grp][ln][c];
            s_dv[grp][ln] = s;
        }
    }
    __syncthreads();
    if (valid) {
        float a = b_pn2[ln];
        for (int o = 0; o < kF; o++) a += s_sp1[grp][o] * w_pn2[o * kF + ln];
        s_spat[grp][ln] = silu_f(a);
        if (ln == 0) {
            float s = 0.f;
            for (int o = 0; o < kF; o++) s += s_g1[grp][o] * w_v2[o];
            s_gate[grp] = 2.f / (1.f + __expf(-s));
        }
    }
    __syncthreads();
    if (valid) {
        float a = b_n1[ln];
        for (int f = 0; f < kF; f++) a += s_h[grp][f] * w_n1[f * kF + ln];
        for (int c = 0; c < kC; c++)
            a += hisem_g[(size_t)node * kC + c] * w_n1[(kF + c) * kF + ln];
        for (int f = 0; f < kF; f++) a += s_spat[grp][f] * w_n1[(kF + kC + f) * kF + ln];
        s_n1[grp][ln] = silu_f(a);
    }
    __syncthreads();
    if (valid) {
        float a = b_n2[ln];
        for (int o = 0; o < kF; o++) a += s_n1[grp][o] * w_n2[o * kF + ln];
        out_h[(size_t)node * kF + ln] = s_h[grp][ln] + silu_f(a);
        if (ln < 3) {
            float vv = v[(size_t)node * 3 + ln];
            float vu = s_gate[grp] * vv + s_dv[grp][ln];
            out_v[(size_t)node * 3 + ln] = vu;
            out_x[(size_t)node * 3 + ln] = x[(size_t)node * 3 + ln] + vu;
        }
    }
}

// ---------------------------------------------------------------------------
extern "C" void kernel_launch(void* const* d_in, const int* in_sizes, int n_in,
                              void* d_out, int out_size, void* d_ws, size_t ws_size,
                              hipStream_t stream)
{
    const float* h      = (const float*)d_in[0];
    const float* x      = (const float*)d_in[1];
    const float* v      = (const float*)d_in[2];
    const int*   pl     = (const int*)d_in[3];
    const float* w_in   = (const float*)d_in[4];
    const float* b_in   = (const float*)d_in[5];
    const float* w_e1   = (const float*)d_in[6];
    const float* b_e1   = (const float*)d_in[7];
    const float* w_e2   = (const float*)d_in[8];
    const float* b_e2   = (const float*)d_in[9];
    const float* w_att  = (const float*)d_in[10];
    const float* b_att  = (const float*)d_in[11];
    const float* w_n1   = (const float*)d_in[12];
    const float* b_n1   = (const float*)d_in[13];
    const float* w_n2   = (const float*)d_in[14];
    const float* b_n2   = (const float*)d_in[15];
    const float* w_pn1  = (const float*)d_in[16];
    const float* b_pn1  = (const float*)d_in[17];
    const float* w_pn2  = (const float*)d_in[18];
    const float* b_pn2  = (const float*)d_in[19];
    const float* w_v1   = (const float*)d_in[20];
    const float* b_v1   = (const float*)d_in[21];
    const float* w_v2   = (const float*)d_in[22];
    const float* w_xmix = (const float*)d_in[23];
    const float* w_vmix = (const float*)d_in[24];

    const int E_ = in_sizes[3] / 2;
    const int N_ = in_sizes[0] / kF;

    // Workspace carve-up (16B-aligned segments first)
    char* w = (char*)d_ws;
    u16*   wxT     = (u16*)w;   w += (size_t)kC * kC * 2;          // 100352 B (16B mult)
    float* he_g    = (float*)w; w += (size_t)E_ * kF * 4;
    float* logit_g = (float*)w; w += (size_t)E_ * kH * 4;
    float* dir_g   = (float*)w; w += (size_t)E_ * 3 * 4;
    float* m_g     = (float*)w; w += (size_t)N_ * kH * 4;
    float* invs_g  = (float*)w; w += (size_t)N_ * kH * 4;
    float* comb_g  = (float*)w; w += (size_t)N_ * 3 * kC * 4;      // contiguous with hisem
    float* hisem_g = (float*)w; w += (size_t)N_ * kC * 4;
    int* counts    = (int*)w;   w += (size_t)N_ * 4;
    int* offs      = (int*)w;   w += (size_t)(N_ + 1) * 4;
    int* cursor    = (int*)w;   w += (size_t)N_ * 4;
    int* sorted    = (int*)w;   w += (size_t)E_ * 4;

    float* out_h = (float*)d_out;
    float* out_x = out_h + (size_t)N_ * kF;
    float* out_v = out_x + (size_t)N_ * 3;

    init_kernel<<<dim3((kC * kC + 255) / 256), dim3(256), 0, stream>>>(
        w_xmix, wxT, counts, cursor, N_);

    // zero accumulation buffers (comb + hisem adjacent: one memset)
    hipMemsetAsync(comb_g, 0, (size_t)N_ * 4 * kC * 4, stream);

    edge_kernel<<<dim3((E_ + 255) / 256), dim3(256), 0, stream>>>(
        h, x, pl, E_, w_in, b_in, w_e1, b_e1, w_e2, b_e2, w_att, b_att,
        he_g, logit_g, dir_g, counts);

    scan_kernel<<<dim3(1), dim3(1024), 0, stream>>>(counts, offs, N_);

    scatter_kernel<<<dim3((E_ + 255) / 256), dim3(256), 0, stream>>>(
        pl, offs, cursor, sorted, E_);

    stats_kernel<<<dim3((N_ + 3) / 4), dim3(256), 0, stream>>>(
        logit_g, offs, sorted, m_g, invs_g, N_);

    xmix_kernel<<<dim3((E_ + kM - 1) / kM), dim3(256), 0, stream>>>(
        he_g, logit_g, dir_g, pl, sorted, m_g, invs_g, wxT, E_,
        comb_g, hisem_g);

    final_kernel<<<dim3((N_ + 7) / 8), dim3(256), 0, stream>>>(
        h, x, v, comb_g, hisem_g, offs,
        w_n1, b_n1, w_n2, b_n2, w_pn1, b_pn1, w_pn2, b_pn2,
        w_v1, b_v1, w_v2, w_vmix, out_h, out_x, out_v, N_);
}

// Round 5
// 524.628 us; speedup vs baseline: 2.3977x; 1.3928x over previous
//
#include <hip/hip_runtime.h>
#include <math.h>

typedef unsigned short u16;
typedef __attribute__((ext_vector_type(8))) short bf16x8;
typedef __attribute__((ext_vector_type(4))) float f32x4;

// Problem constants (match reference)
constexpr int kF    = 32;    // nr_atom_basis
constexpr int kH    = 7;     // heads
constexpr int kC    = 224;   // F*H
constexpr int kRBF  = 50;
constexpr int kM    = 128;   // edges per xmix block
constexpr int kStr  = 232;   // LDS row stride (bf16 elems; 464B = 29*16B)
constexpr int kCk   = 32;    // edge chunk in node kernel
constexpr float kCut = 5.0f;
constexpr float kEps = 1e-8f;

__device__ __forceinline__ float silu_f(float a) { return a / (1.f + __expf(-a)); }
__device__ __forceinline__ float tanh_f(float x) {
    x = fminf(fmaxf(x, -15.f), 15.f);
    float e = __expf(2.f * x);
    return (e - 1.f) / (e + 1.f);
}
__device__ __forceinline__ float bf2f(u16 u) {
    union { unsigned int i; float f; } v; v.i = ((unsigned int)u) << 16; return v.f;
}
__device__ __forceinline__ u16 f2bf(float f) {
    union { float f; unsigned int i; } v; v.f = f;
    unsigned int x = v.i;
    unsigned int round = ((x >> 16) & 1u) + 0x7fffu;
    return (u16)((x + round) >> 16);
}

// ---------------------------------------------------------------------------
// K0: zero histogram + cursors; build wxT (bf16, transposed w_xmix)
// ---------------------------------------------------------------------------
__global__ __launch_bounds__(256) void init_kernel(
    const float* __restrict__ wx, u16* __restrict__ wxT,
    int* __restrict__ counts, int* __restrict__ cursor, int N_)
{
    int idx = blockIdx.x * 256 + threadIdx.x;
    if (idx < kC * kC) {
        int c = idx / kC, k = idx - c * kC;      // wxT[c][k] = wx[k][c]
        wxT[idx] = f2bf(wx[k * kC + c]);
    }
    if (idx < N_) { counts[idx] = 0; cursor[idx] = 0; }
}

// ---------------------------------------------------------------------------
// K1: per-edge geometry + edge MLP + attention logits; histogram of idx_i
// ---------------------------------------------------------------------------
__global__ __launch_bounds__(256) void edge_kernel(
    const float* __restrict__ h, const float* __restrict__ x,
    const int* __restrict__ pl, int E_,
    const float* __restrict__ w_in, const float* __restrict__ b_in,
    const float* __restrict__ w_e1, const float* __restrict__ b_e1,
    const float* __restrict__ w_e2, const float* __restrict__ b_e2,
    const float* __restrict__ w_att, const float* __restrict__ b_att,
    float* __restrict__ he_g, float* __restrict__ logit_g,
    float* __restrict__ dir_g, int* __restrict__ counts)
{
    __shared__ float s_win[64 * kRBF];   // (2F, NRBF)
    __shared__ float s_we1[115 * kF];    // (2F+NRBF+1, F)
    __shared__ float s_we2[kF * kF];
    __shared__ float s_watt[kF * kH];
    __shared__ float s_bin[kRBF], s_be1[kF], s_be2[kF], s_batt[kH];

    int t = threadIdx.x;
    for (int idx = t; idx < 64 * kRBF; idx += 256) s_win[idx] = w_in[idx];
    for (int idx = t; idx < 115 * kF; idx += 256) s_we1[idx] = w_e1[idx];
    for (int idx = t; idx < kF * kF; idx += 256) s_we2[idx] = w_e2[idx];
    for (int idx = t; idx < kF * kH; idx += 256) s_watt[idx] = w_att[idx];
    if (t < kRBF) s_bin[t] = b_in[t];
    if (t < kF) { s_be1[t] = b_e1[t]; s_be2[t] = b_e2[t]; }
    if (t < kH) s_batt[t] = b_att[t];
    __syncthreads();

    int e = blockIdx.x * 256 + t;
    if (e >= E_) return;
    int i = pl[e], j = pl[E_ + e];

    float xi0 = x[i * 3 + 0], xi1 = x[i * 3 + 1], xi2 = x[i * 3 + 2];
    float r0 = x[j * 3 + 0] - xi0;
    float r1 = x[j * 3 + 1] - xi1;
    float r2 = x[j * 3 + 2] - xi2;
    float d = sqrtf(r0 * r0 + r1 * r1 + r2 * r2);
    float inv = 1.0f / (d + kEps);
    dir_g[(size_t)e * 3 + 0] = r0 * inv;
    dir_g[(size_t)e * 3 + 1] = r1 * inv;
    dir_g[(size_t)e * 3 + 2] = r2 * inv;

    const float* hi = h + (size_t)i * kF;
    const float* hj = h + (size_t)j * kF;

    // filt = rbf * (h_cat @ w_in + b_in)
    float facc[kRBF];
#pragma unroll
    for (int n = 0; n < kRBF; n++) facc[n] = 0.f;
    for (int f = 0; f < kF; f++) {
        float v = hi[f];
#pragma unroll
        for (int n = 0; n < kRBF; n++) facc[n] += v * s_win[f * kRBF + n];
    }
    for (int f = 0; f < kF; f++) {
        float v = hj[f];
#pragma unroll
        for (int n = 0; n < kRBF; n++) facc[n] += v * s_win[(kF + f) * kRBF + n];
    }
    const float invw = 49.0f / kCut;
    float dw = d * invw;
#pragma unroll
    for (int n = 0; n < kRBF; n++) {
        float a = dw - (float)n;
        facc[n] = __expf(-0.5f * a * a) * (facc[n] + s_bin[n]);
    }

    // t1 = silu(edge_in @ w_e1 + b_e1)
    float t1[kF];
#pragma unroll
    for (int o = 0; o < kF; o++) t1[o] = s_be1[o];
    for (int f = 0; f < kF; f++) {
        float v = hi[f];
#pragma unroll
        for (int o = 0; o < kF; o++) t1[o] += v * s_we1[f * kF + o];
    }
    for (int f = 0; f < kF; f++) {
        float v = hj[f];
#pragma unroll
        for (int o = 0; o < kF; o++) t1[o] += v * s_we1[(kF + f) * kF + o];
    }
#pragma unroll
    for (int n = 0; n < kRBF; n++) {
        float v = facc[n];
#pragma unroll
        for (int o = 0; o < kF; o++) t1[o] += v * s_we1[(64 + n) * kF + o];
    }
#pragma unroll
    for (int o = 0; o < kF; o++) t1[o] += d * s_we1[114 * kF + o];
#pragma unroll
    for (int o = 0; o < kF; o++) t1[o] = silu_f(t1[o]);

    // h_ij_edge = t1 @ w_e2 + b_e2
    float he[kF];
#pragma unroll
    for (int o = 0; o < kF; o++) he[o] = s_be2[o];
#pragma unroll
    for (int o = 0; o < kF; o++) {
        float v = t1[o];
#pragma unroll
        for (int o2 = 0; o2 < kF; o2++) he[o2] += v * s_we2[o * kF + o2];
    }
    float4* hp = (float4*)(he_g + (size_t)e * kF);
#pragma unroll
    for (int q = 0; q < 8; q++) {
        float4 v4;
        v4.x = he[4 * q + 0]; v4.y = he[4 * q + 1];
        v4.z = he[4 * q + 2]; v4.w = he[4 * q + 3];
        hp[q] = v4;
    }

    // att logits: celu(he @ w_att + b_att, alpha=2) * cutoff(d)
    float aw[kH];
#pragma unroll
    for (int hh = 0; hh < kH; hh++) aw[hh] = s_batt[hh];
#pragma unroll
    for (int f = 0; f < kF; f++) {
        float v = he[f];
#pragma unroll
        for (int hh = 0; hh < kH; hh++) aw[hh] += v * s_watt[f * kH + hh];
    }
    float cut = 0.f;
    if (d < kCut) cut = 0.5f * (__cosf(0.62831853071795864f * d) + 1.f);
#pragma unroll
    for (int hh = 0; hh < kH; hh++) {
        float a = aw[hh];
        a = (a >= 0.f) ? a : 2.f * (__expf(0.5f * a) - 1.f);
        logit_g[(size_t)e * kH + hh] = a * cut;
    }
    atomicAdd(&counts[i], 1);
}

// ---------------------------------------------------------------------------
// K2: exclusive scan of counts -> offsets (single block, 1024 threads)
// ---------------------------------------------------------------------------
__global__ __launch_bounds__(1024) void scan_kernel(
    const int* __restrict__ counts, int* __restrict__ offsets, int n)
{
    __shared__ int buf[1024];
    __shared__ int carry;
    int t = threadIdx.x;
    if (t == 0) carry = 0;
    __syncthreads();
    for (int base = 0; base < n; base += 1024) {
        int v = (base + t < n) ? counts[base + t] : 0;
        buf[t] = v;
        __syncthreads();
        for (int off = 1; off < 1024; off <<= 1) {
            int xv = (t >= off) ? buf[t - off] : 0;
            __syncthreads();
            buf[t] += xv;
            __syncthreads();
        }
        int c0 = carry;
        if (base + t < n) offsets[base + t] = c0 + buf[t] - v;
        int tot = buf[1023];
        __syncthreads();
        if (t == 0) carry = c0 + tot;
        __syncthreads();
    }
    if (t == 0) offsets[n] = carry;
}

// ---------------------------------------------------------------------------
// K3: scatter edges into CSR order
// ---------------------------------------------------------------------------
__global__ __launch_bounds__(256) void scatter_kernel(
    const int* __restrict__ pl, const int* __restrict__ offsets,
    int* __restrict__ cursor, int* __restrict__ sorted, int E_)
{
    int e = blockIdx.x * 256 + threadIdx.x;
    if (e < E_) {
        int i = pl[e];
        int p = atomicAdd(&cursor[i], 1);
        sorted[offsets[i] + p] = e;
    }
}

// ---------------------------------------------------------------------------
// K4: per-node softmax stats (one 64-lane wave per node, online max/sum)
// ---------------------------------------------------------------------------
__global__ __launch_bounds__(256) void stats_kernel(
    const float* __restrict__ logit_g, const int* __restrict__ offsets,
    const int* __restrict__ sorted,
    float* __restrict__ m_g, float* __restrict__ invs_g, int N_)
{
    int wave = threadIdx.x >> 6;
    int lane = threadIdx.x & 63;
    int node = blockIdx.x * 4 + wave;
    if (node >= N_) return;
    int base = offsets[node];
    int deg  = offsets[node + 1] - base;

    for (int hh = 0; hh < kH; hh++) {
        float m = -1e30f, s = 0.f;
        for (int e = lane; e < deg; e += 64) {
            int ed = sorted[base + e];
            float vv = logit_g[(size_t)ed * kH + hh];
            if (vv > m) { s *= __expf(m - vv); m = vv; }
            s += __expf(vv - m);
        }
#pragma unroll
        for (int off = 32; off >= 1; off >>= 1) {
            float mo = __shfl_xor(m, off);
            float so = __shfl_xor(s, off);
            float mn = fmaxf(m, mo);
            s = s * __expf(m - mn) + so * __expf(mo - mn);
            m = mn;
        }
        if (lane == 0) {
            m_g[(size_t)node * kH + hh] = m;
            invs_g[(size_t)node * kH + hh] = (s > 0.f) ? 1.0f / s : 0.f;
        }
    }
}

// ---------------------------------------------------------------------------
// K5: MFMA xmix kernel. T[pos][c] = tanh(sem @ wx) stored bf16, CSR order.
// No atomics: D tiles staged through reused LDS, coalesced dwordx4 dump.
// ---------------------------------------------------------------------------
__global__ __launch_bounds__(256) void xmix_kernel(
    const float* __restrict__ he_g, const float* __restrict__ logit_g,
    const int* __restrict__ pl, const int* __restrict__ sorted,
    const float* __restrict__ m_g, const float* __restrict__ invs_g,
    const u16* __restrict__ wxT, int E_, u16* __restrict__ T_g)
{
    __shared__ u16   s_buf[kM][kStr];      // 59392 B: sem, then T staging
    __shared__ float s_att[kM][kH];        // 3584 B
    __shared__ int   s_ed[kM];             // 512 B

    int t = threadIdx.x;
    int T0 = blockIdx.x * kM;

    if (t < kM) {
        int gi = T0 + t;
        s_ed[t] = (gi < E_) ? sorted[gi] : -1;
    }
    __syncthreads();

    for (int idx = t; idx < kM * kH; idx += 256) {
        int e = idx / kH, hh = idx - e * kH;
        int ed = s_ed[e];
        float a = 0.f;
        if (ed >= 0) {
            int nd = pl[ed];
            a = __expf(logit_g[(size_t)ed * kH + hh] - m_g[(size_t)nd * kH + hh])
                * invs_g[(size_t)nd * kH + hh];
        }
        s_att[e][hh] = a;
    }
    __syncthreads();

    // build sem[e][c] = he[e][c/7] * att[e][c%7] in bf16; thread owns (e, f)
#pragma unroll
    for (int p = 0; p < kM * kF / 256; p++) {       // 16 iters
        int idx = t + 256 * p;
        int e = idx >> 5, f = idx & 31;
        int ed = s_ed[e];
        float hv = (ed >= 0) ? he_g[(size_t)ed * kF + f] : 0.f;
        u16 sw[7];
#pragma unroll
        for (int hh = 0; hh < kH; hh++) sw[hh] = f2bf(hv * s_att[e][hh]);
        u16* dst = &s_buf[e][f * 7];
        if ((f & 1) == 0) {
            *(unsigned int*)(dst)     = (unsigned int)sw[0] | ((unsigned int)sw[1] << 16);
            *(unsigned int*)(dst + 2) = (unsigned int)sw[2] | ((unsigned int)sw[3] << 16);
            *(unsigned int*)(dst + 4) = (unsigned int)sw[4] | ((unsigned int)sw[5] << 16);
            dst[6] = sw[6];
        } else {
            dst[0] = sw[0];
            *(unsigned int*)(dst + 1) = (unsigned int)sw[1] | ((unsigned int)sw[2] << 16);
            *(unsigned int*)(dst + 3) = (unsigned int)sw[3] | ((unsigned int)sw[4] << 16);
            *(unsigned int*)(dst + 5) = (unsigned int)sw[5] | ((unsigned int)sw[6] << 16);
        }
    }
    __syncthreads();

    // MFMA: wave w owns edges [32w, 32w+32) = 2 row-tiles of 16
    int w    = t >> 6;
    int lane = t & 63;
    int quad = lane >> 4;
    int l15  = lane & 15;

    // persistent A-fragments (after this, s_buf is reusable)
    bf16x8 afr[2][7];
#pragma unroll
    for (int rt = 0; rt < 2; rt++)
#pragma unroll
        for (int kt = 0; kt < 7; kt++)
            afr[rt][kt] = *(const bf16x8*)&s_buf[32 * w + 16 * rt + l15][kt * 32 + quad * 8];

    bf16x8 bA[7], bB[7];
    {
        const u16* bp = wxT + (size_t)l15 * kC + quad * 8;
#pragma unroll
        for (int kt = 0; kt < 7; kt++) bA[kt] = *(const bf16x8*)(bp + kt * 32);
    }
    __syncthreads();   // all waves have their A-frags; s_buf now T staging

    for (int ct = 0; ct < 14; ct++) {
        bf16x8* cur = (ct & 1) ? bB : bA;
        bf16x8* nxt = (ct & 1) ? bA : bB;
        if (ct < 13) {
            const u16* bp = wxT + (size_t)((ct + 1) * 16 + l15) * kC + quad * 8;
#pragma unroll
            for (int kt = 0; kt < 7; kt++) nxt[kt] = *(const bf16x8*)(bp + kt * 32);
        }
        f32x4 acc0 = {0.f, 0.f, 0.f, 0.f};
        f32x4 acc1 = {0.f, 0.f, 0.f, 0.f};
#pragma unroll
        for (int kt = 0; kt < 7; kt++) {
            acc0 = __builtin_amdgcn_mfma_f32_16x16x32_bf16(afr[0][kt], cur[kt], acc0, 0, 0, 0);
            acc1 = __builtin_amdgcn_mfma_f32_16x16x32_bf16(afr[1][kt], cur[kt], acc1, 0, 0, 0);
        }
        // D layout: reg r of accS holds row (32w + 16S + quad*4 + r), col ct*16+l15
        int colg = ct * 16 + l15;
#pragma unroll
        for (int s = 0; s < 2; s++) {
            f32x4 ac = s ? acc1 : acc0;
            int rbase = 32 * w + 16 * s + quad * 4;
#pragma unroll
            for (int r = 0; r < 4; r++)
                s_buf[rbase + r][colg] = f2bf(tanh_f(ac[r]));
        }
    }
    __syncthreads();

    // coalesced dump: 128 rows x 224 cols bf16 -> T_g[(T0+row)*224 + col]
#pragma unroll
    for (int it = 0; it < 14; it++) {
        int idx = t + 256 * it;               // < 3584
        int row = idx / 28, ch = idx - row * 28;
        uint4 vv = *(const uint4*)&s_buf[row][ch * 8];
        *(uint4*)(T_g + ((size_t)(T0 + row) * kC + ch * 8)) = vv;
    }
}

// ---------------------------------------------------------------------------
// K6: one block per node — comb/hisem/cnsq/dv from T rows, then node MLPs.
// Zero global atomics; reads are contiguous CSR rows.
// ---------------------------------------------------------------------------
__global__ __launch_bounds__(256) void node_kernel(
    const float* __restrict__ h, const float* __restrict__ x, const float* __restrict__ v,
    const u16* __restrict__ T_g, const float* __restrict__ he_g,
    const float* __restrict__ logit_g, const float* __restrict__ dir_g,
    const int* __restrict__ offsets, const int* __restrict__ sorted,
    const float* __restrict__ m_g, const float* __restrict__ invs_g,
    const float* __restrict__ w_n1, const float* __restrict__ b_n1,
    const float* __restrict__ w_n2, const float* __restrict__ b_n2,
    const float* __restrict__ w_pn1, const float* __restrict__ b_pn1,
    const float* __restrict__ w_pn2, const float* __restrict__ b_pn2,
    const float* __restrict__ w_v1, const float* __restrict__ b_v1,
    const float* __restrict__ w_v2, const float* __restrict__ w_vmix,
    float* __restrict__ out_h, float* __restrict__ out_x, float* __restrict__ out_v,
    int N_)
{
    __shared__ u16   s_T[kCk][kC];        // 14336 B
    __shared__ float s_he[kCk][kF];       // 4096 B
    __shared__ float s_att[kCk][kH];      // 896 B
    __shared__ float s_dir[kCk][3];       // 384 B
    __shared__ int   s_ed[kCk];
    __shared__ float s_cm[3][kC];         // comb mean
    __shared__ float s_cnsq[kC];
    __shared__ float s_hisem[kC];
    __shared__ float s_hn[kF], s_sp1[kF], s_spat[kF], s_n1[kF], s_g1[kF];
    __shared__ float s_gate, s_dv[3];

    int node = blockIdx.x;
    int t = threadIdx.x;
    int base = offsets[node];
    int deg  = offsets[node + 1] - base;

    float c0 = 0.f, c1 = 0.f, c2 = 0.f, hs = 0.f;   // thread t<kC accumulators
    int f7 = t / kH, h7 = t - f7 * kH;              // valid for t<kC

    for (int e0 = 0; e0 < deg; e0 += kCk) {
        int ce = min(kCk, deg - e0);
        if (t < ce) s_ed[t] = sorted[base + e0 + t];
        __syncthreads();
        // stage T rows (contiguous CSR positions)
        for (int idx = t; idx < ce * 28; idx += 256) {
            int el = idx / 28, ch = idx - el * 28;
            uint4 vv = *(const uint4*)(T_g + ((size_t)(base + e0 + el) * kC + ch * 8));
            *(uint4*)&s_T[el][ch * 8] = vv;
        }
        for (int idx = t; idx < ce * 8; idx += 256) {
            int el = idx >> 3, q = idx & 7;
            ((float4*)s_he[el])[q] = ((const float4*)(he_g + (size_t)s_ed[el] * kF))[q];
        }
        for (int idx = t; idx < ce * kH; idx += 256) {
            int el = idx / kH, hh = idx - el * kH;
            s_att[el][hh] = __expf(logit_g[(size_t)s_ed[el] * kH + hh]
                                   - m_g[(size_t)node * kH + hh])
                            * invs_g[(size_t)node * kH + hh];
        }
        for (int idx = t; idx < ce * 3; idx += 256) {
            int el = idx / 3, xx = idx - el * 3;
            s_dir[el][xx] = dir_g[(size_t)s_ed[el] * 3 + xx];
        }
        __syncthreads();
        if (t < kC) {
            for (int el = 0; el < ce; el++) {
                float Tv = bf2f(s_T[el][t]);
                c0 += Tv * s_dir[el][0];
                c1 += Tv * s_dir[el][1];
                c2 += Tv * s_dir[el][2];
                hs += s_he[el][f7] * s_att[el][h7];
            }
        }
        __syncthreads();
    }

    float invc = 1.f / fmaxf((float)deg, 1.f);
    if (t < kC) {
        float m0 = c0 * invc, m1 = c1 * invc, m2 = c2 * invc;
        s_cm[0][t] = m0; s_cm[1][t] = m1; s_cm[2][t] = m2;
        s_cnsq[t] = m0 * m0 + m1 * m1 + m2 * m2;
        s_hisem[t] = hs;
    }
    if (t >= 224 && t < 256) s_hn[t - 224] = h[(size_t)node * kF + (t - 224)];
    __syncthreads();

    // MLP chain
    if (t < kF) {
        float a = b_pn1[t];
        for (int c = 0; c < kC; c++) a += s_cnsq[c] * w_pn1[c * kF + t];
        s_sp1[t] = silu_f(a);
    } else if (t >= 64 && t < 96) {
        int o = t - 64;
        float a = b_v1[o];
        for (int f = 0; f < kF; f++) a += s_hn[f] * w_v1[f * kF + o];
        s_g1[o] = silu_f(a);
    } else if (t >= 128 && t < 131) {
        int xx = t - 128;
        float a = 0.f;
        for (int c = 0; c < kC; c++) a += w_vmix[c] * s_cm[xx][c];
        s_dv[xx] = a;
    }
    __syncthreads();
    if (t < kF) {
        float a = b_pn2[t];
        for (int o = 0; o < kF; o++) a += s_sp1[o] * w_pn2[o * kF + t];
        s_spat[t] = silu_f(a);
    } else if (t == 64) {
        float a = 0.f;
        for (int o = 0; o < kF; o++) a += s_g1[o] * w_v2[o];
        s_gate = 2.f / (1.f + __expf(-a));
    }
    __syncthreads();
    if (t < kF) {
        float a = b_n1[t];
        for (int f = 0; f < kF; f++) a += s_hn[f] * w_n1[f * kF + t];
        for (int c = 0; c < kC; c++) a += s_hisem[c] * w_n1[(kF + c) * kF + t];
        for (int f = 0; f < kF; f++) a += s_spat[f] * w_n1[(kF + kC + f) * kF + t];
        s_n1[t] = silu_f(a);
    }
    __syncthreads();
    if (t < kF) {
        float a = b_n2[t];
        for (int o = 0; o < kF; o++) a += s_n1[o] * w_n2[o * kF + t];
        out_h[(size_t)node * kF + t] = s_hn[t] + silu_f(a);
    } else if (t >= 64 && t < 67) {
        int xx = t - 64;
        float vv = v[(size_t)node * 3 + xx];
        float vu = s_gate * vv + s_dv[xx];
        out_v[(size_t)node * 3 + xx] = vu;
        out_x[(size_t)node * 3 + xx] = x[(size_t)node * 3 + xx] + vu;
    }
}

// ---------------------------------------------------------------------------
extern "C" void kernel_launch(void* const* d_in, const int* in_sizes, int n_in,
                              void* d_out, int out_size, void* d_ws, size_t ws_size,
                              hipStream_t stream)
{
    const float* h      = (const float*)d_in[0];
    const float* x      = (const float*)d_in[1];
    const float* v      = (const float*)d_in[2];
    const int*   pl     = (const int*)d_in[3];
    const float* w_in   = (const float*)d_in[4];
    const float* b_in   = (const float*)d_in[5];
    const float* w_e1   = (const float*)d_in[6];
    const float* b_e1   = (const float*)d_in[7];
    const float* w_e2   = (const float*)d_in[8];
    const float* b_e2   = (const float*)d_in[9];
    const float* w_att  = (const float*)d_in[10];
    const float* b_att  = (const float*)d_in[11];
    const float* w_n1   = (const float*)d_in[12];
    const float* b_n1   = (const float*)d_in[13];
    const float* w_n2   = (const float*)d_in[14];
    const float* b_n2   = (const float*)d_in[15];
    const float* w_pn1  = (const float*)d_in[16];
    const float* b_pn1  = (const float*)d_in[17];
    const float* w_pn2  = (const float*)d_in[18];
    const float* b_pn2  = (const float*)d_in[19];
    const float* w_v1   = (const float*)d_in[20];
    const float* b_v1   = (const float*)d_in[21];
    const float* w_v2   = (const float*)d_in[22];
    const float* w_xmix = (const float*)d_in[23];
    const float* w_vmix = (const float*)d_in[24];

    const int E_ = in_sizes[3] / 2;
    const int N_ = in_sizes[0] / kF;
    const int nblk = (E_ + kM - 1) / kM;

    // Workspace carve-up (~125 MB; all segments 16B-aligned)
    char* w = (char*)d_ws;
    u16*   wxT     = (u16*)w;   w += (size_t)kC * kC * 2;            // 100352 B
    u16*   T_g     = (u16*)w;   w += (size_t)nblk * kM * kC * 2;     // ~89.7 MB
    float* he_g    = (float*)w; w += (size_t)E_ * kF * 4;
    float* logit_g = (float*)w; w += (size_t)E_ * kH * 4;
    float* dir_g   = (float*)w; w += (size_t)E_ * 3 * 4;
    float* m_g     = (float*)w; w += (size_t)N_ * kH * 4;
    float* invs_g  = (float*)w; w += (size_t)N_ * kH * 4;
    int* counts    = (int*)w;   w += (size_t)N_ * 4;
    int* offs      = (int*)w;   w += (size_t)(N_ + 1) * 4;
    int* cursor    = (int*)w;   w += (size_t)N_ * 4;
    int* sorted    = (int*)w;   w += (size_t)E_ * 4;

    float* out_h = (float*)d_out;
    float* out_x = out_h + (size_t)N_ * kF;
    float* out_v = out_x + (size_t)N_ * 3;

    init_kernel<<<dim3((kC * kC + 255) / 256), dim3(256), 0, stream>>>(
        w_xmix, wxT, counts, cursor, N_);

    edge_kernel<<<dim3((E_ + 255) / 256), dim3(256), 0, stream>>>(
        h, x, pl, E_, w_in, b_in, w_e1, b_e1, w_e2, b_e2, w_att, b_att,
        he_g, logit_g, dir_g, counts);

    scan_kernel<<<dim3(1), dim3(1024), 0, stream>>>(counts, offs, N_);

    scatter_kernel<<<dim3((E_ + 255) / 256), dim3(256), 0, stream>>>(
        pl, offs, cursor, sorted, E_);

    stats_kernel<<<dim3((N_ + 3) / 4), dim3(256), 0, stream>>>(
        logit_g, offs, sorted, m_g, invs_g, N_);

    xmix_kernel<<<dim3(nblk), dim3(256), 0, stream>>>(
        he_g, logit_g, pl, sorted, m_g, invs_g, wxT, E_, T_g);

    node_kernel<<<dim3(N_), dim3(256), 0, stream>>>(
        h, x, v, T_g, he_g, logit_g, dir_g, offs, sorted, m_g, invs_g,
        w_n1, b_n1, w_n2, b_n2, w_pn1, b_pn1, w_pn2, b_pn2,
        w_v1, b_v1, w_v2, w_vmix, out_h, out_x, out_v, N_);
}